// Round 5
// baseline (1395.225 us; speedup 1.0000x reference)
//
#include <hip/hip_runtime.h>
#include <cstdint>
#include <cstddef>
#include <math.h>

// AtomSelector: B=4096, A=4096, H=768, L=4.
// R5: gi GEMM removed algebraically (gi = P[b] + AE[idx_prev[b]], P/AE
//     precomputed once); gumbel+mask+rowmax fused into head-GEMM epilogue;
//     merged preamble; sample_lite = eps-window collect + exact refine.
// PRNG: JAX threefry2x32 partitionable scheme (verified exact since R0).

#define KB 4096
#define KA 4096
#define KH 768
#define KL 4

typedef __attribute__((ext_vector_type(8))) short bf16x8;
typedef __attribute__((ext_vector_type(4))) float f32x4;

__host__ __device__ inline unsigned rotl32(unsigned x, int d) {
  return (x << d) | (x >> (32 - d));
}

// Threefry-2x32, 20 rounds
__host__ __device__ inline void tf2x32(unsigned k0, unsigned k1,
                                       unsigned x0, unsigned x1,
                                       unsigned& o0, unsigned& o1) {
  unsigned ks2 = k0 ^ k1 ^ 0x1BD11BDAu;
  x0 += k0; x1 += k1;
#define TF_R(r) { x0 += x1; x1 = rotl32(x1, (r)); x1 ^= x0; }
  TF_R(13) TF_R(15) TF_R(26) TF_R(6)
  x0 += k1;  x1 += ks2 + 1u;
  TF_R(17) TF_R(29) TF_R(16) TF_R(24)
  x0 += ks2; x1 += k0 + 2u;
  TF_R(13) TF_R(15) TF_R(26) TF_R(6)
  x0 += k0;  x1 += k1 + 3u;
  TF_R(17) TF_R(29) TF_R(16) TF_R(24)
  x0 += k1;  x1 += ks2 + 4u;
  TF_R(13) TF_R(15) TF_R(26) TF_R(6)
  x0 += ks2; x1 += k0 + 5u;
#undef TF_R
  o0 = x0; o1 = x1;
}

__device__ inline ushort f2bf(float f) {
  unsigned u = __float_as_uint(f);
  unsigned r = (u + 0x7fffu + ((u >> 16) & 1u)) >> 16;
  return (ushort)r;
}
__device__ inline float bf2f(ushort h) {
  return __uint_as_float(((unsigned)h) << 16);
}

__device__ inline float gumbel_at(unsigned s0, unsigned s1, unsigned ctr) {
  unsigned o0, o1;
  tf2x32(s0, s1, 0u, ctr, o0, o1);
  unsigned bits = o0 ^ o1;
  float f = __uint_as_float((bits >> 9) | 0x3f800000u) - 1.0f;
  const float TINY = 1.17549435e-38f;
  float u = fmaxf(TINY, f + TINY);
  return -logf(-logf(u));
}

// Monotone float <-> uint key for atomicMax on floats.
__device__ inline unsigned fkey(float f) {
  unsigned u = __float_as_uint(f);
  return (u & 0x80000000u) ? ~u : (u | 0x80000000u);
}
__device__ inline float keyf(unsigned k) {
  unsigned u = (k & 0x80000000u) ? (k & 0x7fffffffu) : ~k;
  return __uint_as_float(u);
}

// ---------------------------------------------------------------------------
// gemm3_nt: C[M,N] = A[M,768] @ W[N,768]^T via bf16x2-split MFMA (3 products).
// 256 thr / 4 waves; BM=BN=128, BK=64; wave -> 64x64 (4x4 of 16x16 tiles).
// LDS: 4 planes, global_load_lds width=16, XOR-swizzled chunk slots.
// ---------------------------------------------------------------------------
__global__ __launch_bounds__(256) void gemm3_nt(
    const ushort* __restrict__ Ahi, const ushort* __restrict__ Alo,
    const ushort* __restrict__ Bhi, const ushort* __restrict__ Blo,
    float* __restrict__ C, long long ldc) {
  __shared__ ushort smem[4 * 128 * 64];
  const int tid = threadIdx.x;
  const int wave = tid >> 6;
  const int lane = tid & 63;
  const long long bm = (long long)blockIdx.y * 128;
  const long long bn = (long long)blockIdx.x * 128;
  const int wm = (wave & 1) * 64;
  const int wn = (wave >> 1) * 64;

  f32x4 acc[4][4];
#pragma unroll
  for (int i = 0; i < 4; ++i)
#pragma unroll
    for (int j = 0; j < 4; ++j) acc[i][j] = (f32x4){0.f, 0.f, 0.f, 0.f};

  const int r = lane >> 3;
  const int csrc = (lane & 7) ^ r;
  const int m15 = lane & 15;
  const int kg = (lane >> 4) & 3;

  for (int kt = 0; kt < 12; ++kt) {
    const int k0 = kt * 64;
#pragma unroll
    for (int s = 0; s < 4; ++s) {
      const int m0 = wave * 32 + s * 8;
      const long long arow = (bm + m0 + r) * KH + k0 + csrc * 8;
      const long long brow = (bn + m0 + r) * KH + k0 + csrc * 8;
      __builtin_amdgcn_global_load_lds(
          (const __attribute__((address_space(1))) void*)(Ahi + arow),
          (__attribute__((address_space(3))) void*)&smem[0 * 8192 + m0 * 64], 16, 0, 0);
      __builtin_amdgcn_global_load_lds(
          (const __attribute__((address_space(1))) void*)(Alo + arow),
          (__attribute__((address_space(3))) void*)&smem[1 * 8192 + m0 * 64], 16, 0, 0);
      __builtin_amdgcn_global_load_lds(
          (const __attribute__((address_space(1))) void*)(Bhi + brow),
          (__attribute__((address_space(3))) void*)&smem[2 * 8192 + m0 * 64], 16, 0, 0);
      __builtin_amdgcn_global_load_lds(
          (const __attribute__((address_space(1))) void*)(Blo + brow),
          (__attribute__((address_space(3))) void*)&smem[3 * 8192 + m0 * 64], 16, 0, 0);
    }
    __syncthreads();
#pragma unroll
    for (int ks = 0; ks < 2; ++ks) {
      bf16x8 ah[4], al[4], bh[4], bl[4];
#pragma unroll
      for (int i = 0; i < 4; ++i) {
        const int m = wm + i * 16 + m15;
        const int slot = (ks * 4 + kg) ^ (lane & 7);
        ah[i] = *(const bf16x8*)&smem[0 * 8192 + m * 64 + slot * 8];
        al[i] = *(const bf16x8*)&smem[1 * 8192 + m * 64 + slot * 8];
        const int n = wn + i * 16 + m15;
        bh[i] = *(const bf16x8*)&smem[2 * 8192 + n * 64 + slot * 8];
        bl[i] = *(const bf16x8*)&smem[3 * 8192 + n * 64 + slot * 8];
      }
#pragma unroll
      for (int i = 0; i < 4; ++i)
#pragma unroll
        for (int j = 0; j < 4; ++j) {
          acc[i][j] = __builtin_amdgcn_mfma_f32_16x16x32_bf16(ah[i], bh[j], acc[i][j], 0, 0, 0);
          acc[i][j] = __builtin_amdgcn_mfma_f32_16x16x32_bf16(ah[i], bl[j], acc[i][j], 0, 0, 0);
          acc[i][j] = __builtin_amdgcn_mfma_f32_16x16x32_bf16(al[i], bh[j], acc[i][j], 0, 0, 0);
        }
    }
    __syncthreads();
  }
  const int rq = (lane >> 4) * 4;
#pragma unroll
  for (int i = 0; i < 4; ++i)
#pragma unroll
    for (int j = 0; j < 4; ++j) {
      const long long n = bn + wn + j * 16 + m15;
#pragma unroll
      for (int rg = 0; rg < 4; ++rg) {
        const long long m = bm + wm + i * 16 + rq + rg;
        C[m * ldc + n] = acc[i][j][rg];
      }
    }
}

// ---------------------------------------------------------------------------
// Head GEMM (single-product bf16) with fused epilogue:
// v = logit + head_b + gumbel (masked, per reference mask state machine),
// written to d_out[:, j, :]; per-row max merged into vmk via keyed atomicMax.
// ---------------------------------------------------------------------------
__global__ __launch_bounds__(256) void gemm1_head_epi(
    const ushort* __restrict__ Ahi, const ushort* __restrict__ Bhi,
    float* __restrict__ out, const float* __restrict__ head_b,
    const float* __restrict__ x_, const unsigned char* __restrict__ mask,
    const unsigned char* __restrict__ empty, const int* __restrict__ idxbuf,
    unsigned* __restrict__ vmk, int j, unsigned s0, unsigned s1) {
  __shared__ ushort smem[2 * 128 * 64];
  __shared__ unsigned srowkey[128];
  const int tid = threadIdx.x;
  const int wave = tid >> 6;
  const int lane = tid & 63;
  if (tid < 128) srowkey[tid] = 0u;
  const long long bm = (long long)blockIdx.y * 128;
  const long long bn = (long long)blockIdx.x * 128;
  const int wm = (wave & 1) * 64;
  const int wn = (wave >> 1) * 64;

  f32x4 acc[4][4];
#pragma unroll
  for (int i = 0; i < 4; ++i)
#pragma unroll
    for (int jj = 0; jj < 4; ++jj) acc[i][jj] = (f32x4){0.f, 0.f, 0.f, 0.f};

  const int r = lane >> 3;
  const int csrc = (lane & 7) ^ r;
  const int m15 = lane & 15;
  const int kg = (lane >> 4) & 3;

  for (int kt = 0; kt < 12; ++kt) {
    const int k0 = kt * 64;
#pragma unroll
    for (int s = 0; s < 4; ++s) {
      const int m0 = wave * 32 + s * 8;
      const long long arow = (bm + m0 + r) * KH + k0 + csrc * 8;
      const long long brow = (bn + m0 + r) * KH + k0 + csrc * 8;
      __builtin_amdgcn_global_load_lds(
          (const __attribute__((address_space(1))) void*)(Ahi + arow),
          (__attribute__((address_space(3))) void*)&smem[0 * 8192 + m0 * 64], 16, 0, 0);
      __builtin_amdgcn_global_load_lds(
          (const __attribute__((address_space(1))) void*)(Bhi + brow),
          (__attribute__((address_space(3))) void*)&smem[1 * 8192 + m0 * 64], 16, 0, 0);
    }
    __syncthreads();
#pragma unroll
    for (int ks = 0; ks < 2; ++ks) {
      bf16x8 ah[4], bh[4];
#pragma unroll
      for (int i = 0; i < 4; ++i) {
        const int m = wm + i * 16 + m15;
        const int slot = (ks * 4 + kg) ^ (lane & 7);
        ah[i] = *(const bf16x8*)&smem[0 * 8192 + m * 64 + slot * 8];
        const int n = wn + i * 16 + m15;
        bh[i] = *(const bf16x8*)&smem[1 * 8192 + n * 64 + slot * 8];
      }
#pragma unroll
      for (int i = 0; i < 4; ++i)
#pragma unroll
        for (int jj = 0; jj < 4; ++jj)
          acc[i][jj] = __builtin_amdgcn_mfma_f32_16x16x32_bf16(ah[i], bh[jj], acc[i][jj], 0, 0, 0);
    }
    __syncthreads();
  }
  // Epilogue: mask + gumbel + per-row max. C/D: col=lane&15, row=quad*4+reg.
  const int rq = (lane >> 4) * 4;
#pragma unroll
  for (int i = 0; i < 4; ++i)
#pragma unroll
    for (int jj = 0; jj < 4; ++jj) {
      const long long n = bn + wn + jj * 16 + m15;
      const float hb = head_b[n];
#pragma unroll
      for (int rg = 0; rg < 4; ++rg) {
        const int lr = wm + i * 16 + rq + rg;
        const long long m = bm + lr;
        int msk;
        if (j == 0) {
          float xv = x_[m * (long long)KA + n];
          msk = (xv != 0.f) || (empty[m] && n == 0);
        } else {
          msk = (n == 0) || (idxbuf[m] != 0 && mask[m * (long long)KA + n]);
        }
        float v = -INFINITY;
        if (msk) {
          float g = gumbel_at(s0, s1, (unsigned)(m * KA + n));
          v = acc[i][jj][rg] + hb + g;
          atomicMax(&srowkey[lr], fkey(v));
        }
        out[((size_t)m * KL + j) * KA + n] = v;
      }
    }
  __syncthreads();
  if (tid < 128) atomicMax(&vmk[bm + tid], srowkey[tid]);
}

// ---------------------------------------------------------------------------
// Merged preamble: weight/cls/ae bf16 splits, empty[] per row of x_, vmk zero.
// ---------------------------------------------------------------------------
#define CUM1 442368   // w_ih  (3*768*768/4)
#define CUM2 884736   // w_hh
#define CUM3 1671168  // head_w (+4096*768/4)
#define CUM4 2457600  // cls
#define CUM5 3244032  // ae_w
#define PREP_CONV_BLOCKS 12672  // CUM5/256

__global__ void prep(const float* __restrict__ w_ih, const float* __restrict__ w_hh,
                     const float* __restrict__ head_w, const float* __restrict__ cls,
                     const float* __restrict__ ae_w, const float* __restrict__ x_,
                     ushort* __restrict__ WihHi, ushort* __restrict__ WihLo,
                     ushort* __restrict__ WhhHi, ushort* __restrict__ WhhLo,
                     ushort* __restrict__ HwHi, ushort* __restrict__ CAhi,
                     ushort* __restrict__ CAlo, unsigned char* __restrict__ empty,
                     unsigned* __restrict__ vmaxkey) {
  const int blk = blockIdx.x;
  const int tid = threadIdx.x;
  if (blk < PREP_CONV_BLOCKS) {
    const int i = blk * 256 + tid;
    const float* src; ushort* dhi; ushort* dlo; int base; int split; int ofs = 0;
    if (i < CUM1)      { src = w_ih;   dhi = WihHi; dlo = WihLo; base = 0;    split = 1; }
    else if (i < CUM2) { src = w_hh;   dhi = WhhHi; dlo = WhhLo; base = CUM1; split = 1; }
    else if (i < CUM3) { src = head_w; dhi = HwHi;  dlo = 0;     base = CUM2; split = 0; }
    else if (i < CUM4) { src = cls;    dhi = CAhi;  dlo = CAlo;  base = CUM3; split = 1; }
    else               { src = ae_w;   dhi = CAhi;  dlo = CAlo;  base = CUM4; split = 1; ofs = 786432; }
    const int k = i - base;
    float4 v = ((const float4*)src)[k];
    ushort4 h;
    h.x = f2bf(v.x); h.y = f2bf(v.y); h.z = f2bf(v.z); h.w = f2bf(v.w);
    ((ushort4*)dhi)[ofs + k] = h;
    if (split) {
      ushort4 l;
      l.x = f2bf(v.x - bf2f(h.x)); l.y = f2bf(v.y - bf2f(h.y));
      l.z = f2bf(v.z - bf2f(h.z)); l.w = f2bf(v.w - bf2f(h.w));
      ((ushort4*)dlo)[ofs + k] = l;
    }
  } else {
    const int row = blk - PREP_CONV_BLOCKS;  // 0..4095
    __shared__ int scnt[256];
    int cnt = 0;
#pragma unroll
    for (int t = 0; t < 16; ++t)
      cnt += (x_[(size_t)row * KA + tid + (t << 8)] != 0.f) ? 1 : 0;
    scnt[tid] = cnt;
    __syncthreads();
    for (int s = 128; s > 0; s >>= 1) {
      if (tid < s) scnt[tid] += scnt[tid + s];
      __syncthreads();
    }
    if (tid == 0) empty[row] = (scnt[0] == 0) ? 1 : 0;
    if (row < KL * KB / 256) vmaxkey[row * 256 + tid] = 0u;
  }
}

// GRU gates: gi = P[b] (+ AE[idx_prev[b]] if j>0), gh from Gh GEMM (j>0).
__global__ void gru_gate2(const float* __restrict__ PAE, const float* __restrict__ Gh,
                          const int* __restrict__ idxbuf,
                          const float* __restrict__ b_ih, const float* __restrict__ b_hh,
                          float* __restrict__ h, ushort* __restrict__ hHi,
                          ushort* __restrict__ hLo, int first) {
  int i = blockIdx.x * 256 + threadIdx.x;  // over B*H
  int b = i / KH, c = i - b * KH;
  const float* gp = PAE + (size_t)b * (3 * KH);
  float ir = gp[c], iz = gp[c + KH], in_ = gp[c + 2 * KH];
  float hr = b_hh[c], hz = b_hh[c + KH], hn = b_hh[c + 2 * KH];
  float hp = 0.f;
  if (!first) {
    const float* ga = PAE + ((size_t)KB + idxbuf[b]) * (3 * KH);
    ir += ga[c]; iz += ga[c + KH]; in_ += ga[c + 2 * KH];
    const float* gh = Gh + (size_t)b * (3 * KH);
    hr += gh[c]; hz += gh[c + KH]; hn += gh[c + 2 * KH];
    hp = h[i];
  }
  ir += b_ih[c]; iz += b_ih[c + KH]; in_ += b_ih[c + 2 * KH];
  float rr = 1.f / (1.f + expf(-(ir + hr)));
  float z = 1.f / (1.f + expf(-(iz + hz)));
  float n = tanhf(in_ + rr * hn);
  float hv = (1.f - z) * n + z * hp;
  h[i] = hv;
  ushort hh = f2bf(hv);
  hHi[i] = hh;
  hLo[i] = f2bf(hv - bf2f(hh));
}

// One block per row: read precomputed v-row + vmax, eps-window collect,
// exact fp32 refinement, one-hot + mask + idx write.
__global__ __launch_bounds__(256) void sample_lite(
    float* __restrict__ out, const unsigned* __restrict__ vmk,
    unsigned char* __restrict__ mask, int* __restrict__ idxbuf,
    const float* __restrict__ hbuf, const float* __restrict__ head_w,
    const float* __restrict__ head_b, int j, unsigned s0, unsigned s1) {
  const int b = blockIdx.x;
  const int tid = threadIdx.x;
  float* orow = out + ((size_t)b * KL + j) * KA;
  unsigned char* mrow = mask + (size_t)b * KA;
  __shared__ int scand[32];
  __shared__ float sref[32];
  __shared__ int scnt;
  __shared__ int ssel;
  const float EPS = 0.01f;

  if (tid == 0) scnt = 0;
  __syncthreads();
  const float thr = keyf(vmk[b]) - EPS;

  unsigned mbits = 0;
#pragma unroll
  for (int t = 0; t < 16; ++t) {
    int a = tid + (t << 8);
    float v = orow[a];
    if (v != -INFINITY) mbits |= (1u << t);
    if (v >= thr) {
      int slot = atomicAdd(&scnt, 1);
      if (slot < 32) scand[slot] = a;
    }
  }
  __syncthreads();
  const int ncand = min(scnt, 32);

  // exact fp32 refinement; wave w handles candidates w, w+4, ...
  {
    const int wv = tid >> 6;
    const int lane = tid & 63;
    const float4* h4 = (const float4*)(hbuf + (size_t)b * KH);
    for (int t = wv; t < ncand; t += 4) {
      const int a = scand[t];
      const float4* w4 = (const float4*)(head_w + (size_t)a * KH);
      float sum = 0.f;
#pragma unroll
      for (int u = 0; u < 3; ++u) {
        float4 hv = h4[lane + u * 64];
        float4 wv4 = w4[lane + u * 64];
        sum = fmaf(hv.x, wv4.x, sum);
        sum = fmaf(hv.y, wv4.y, sum);
        sum = fmaf(hv.z, wv4.z, sum);
        sum = fmaf(hv.w, wv4.w, sum);
      }
#pragma unroll
      for (int off = 32; off > 0; off >>= 1) sum += __shfl_down(sum, off);
      if (lane == 0) {
        float g = gumbel_at(s0, s1, (unsigned)(b * KA + a));
        sref[t] = sum + head_b[a] + g;
      }
    }
  }
  __syncthreads();

  if (tid == 0) {
    float best = -INFINITY;
    int bsel = KA;
    for (int t = 0; t < ncand; ++t) {
      float v = sref[t];
      int a = scand[t];
      if (v > best || (v == best && a < bsel)) { best = v; bsel = a; }
    }
    ssel = bsel;
  }
  __syncthreads();
  const int sel = ssel;

#pragma unroll
  for (int t = 0; t < 16; ++t) {
    int a = tid + (t << 8);
    int m = (mbits >> t) & 1;
    if (a == sel) m = 0;
    mrow[a] = (unsigned char)m;
    orow[a] = (a == sel) ? 1.f : 0.f;
  }
  if (tid == 0) idxbuf[b] = sel;
}

extern "C" void kernel_launch(void* const* d_in, const int* in_sizes, int n_in,
                              void* d_out, int out_size, void* d_ws, size_t ws_size,
                              hipStream_t stream) {
  const float* cls    = (const float*)d_in[0];
  const float* x_     = (const float*)d_in[1];
  const float* w_ih   = (const float*)d_in[2];
  const float* w_hh   = (const float*)d_in[3];
  const float* b_ih   = (const float*)d_in[4];
  const float* b_hh   = (const float*)d_in[5];
  const float* head_w = (const float*)d_in[6];
  const float* head_b = (const float*)d_in[7];
  const float* ae_w   = (const float*)d_in[8];
  float* out = (float*)d_out;

  char* p = (char*)d_ws;
  ushort* CAhi  = (ushort*)p; p += (size_t)2 * KB * KH * 2;    // 12.6 MB ([cls; ae_w] hi)
  ushort* CAlo  = (ushort*)p; p += (size_t)2 * KB * KH * 2;    // 12.6 MB
  ushort* WihHi = (ushort*)p; p += (size_t)3 * KH * KH * 2;    // 3.5 MB
  ushort* WihLo = (ushort*)p; p += (size_t)3 * KH * KH * 2;
  ushort* WhhHi = (ushort*)p; p += (size_t)3 * KH * KH * 2;
  ushort* WhhLo = (ushort*)p; p += (size_t)3 * KH * KH * 2;
  ushort* HwHi  = (ushort*)p; p += (size_t)KA * KH * 2;        // 6.3 MB
  ushort* hHi   = (ushort*)p; p += (size_t)KB * KH * 2;        // 6.3 MB
  ushort* hLo   = (ushort*)p; p += (size_t)KB * KH * 2;
  float*  hbuf  = (float*)p;  p += (size_t)KB * KH * 4;        // 12.6 MB
  float*  PAE   = (float*)p;  p += (size_t)2 * KB * 3 * KH * 4; // 75.5 MB (P rows 0..4095, AE rows 4096..8191)
  float*  Gh    = (float*)p;  p += (size_t)KB * 3 * KH * 4;    // 37.7 MB
  unsigned char* mask  = (unsigned char*)p; p += (size_t)KB * KA;  // 16.8 MB
  unsigned char* empty = (unsigned char*)p; p += (size_t)KB;
  unsigned* vmaxkey = (unsigned*)p; p += (size_t)KL * KB * 4;  // 64 KB
  int* idxbuf = (int*)p; p += (size_t)KB * 4;

  // Host-side JAX key schedule (partitionable split of key(42)).
  unsigned key0 = 0u, key1 = 42u;
  unsigned sub0[KL], sub1[KL];
  for (int j = 0; j < KL; ++j) {
    unsigned n0, n1, t0, t1;
    tf2x32(key0, key1, 0u, 0u, n0, n1);
    tf2x32(key0, key1, 0u, 1u, t0, t1);
    sub0[j] = t0; sub1[j] = t1;
    key0 = n0; key1 = n1;
  }

  // Preamble: all converts + empty[] + vmax-key zeroing, one launch.
  prep<<<PREP_CONV_BLOCKS + KB, 256, 0, stream>>>(
      w_ih, w_hh, head_w, cls, ae_w, x_,
      WihHi, WihLo, WhhHi, WhhLo, HwHi, CAhi, CAlo, empty, vmaxkey);
  // P = cls @ w_ih^T ; AE = ae_w @ w_ih^T  (one concatenated dispatch).
  gemm3_nt<<<dim3(3 * KH / 128, 2 * KB / 128), 256, 0, stream>>>(
      CAhi, CAlo, WihHi, WihLo, PAE, 3 * KH);

  for (int j = 0; j < KL; ++j) {
    if (j > 0)
      gemm3_nt<<<dim3(3 * KH / 128, KB / 128), 256, 0, stream>>>(
          hHi, hLo, WhhHi, WhhLo, Gh, 3 * KH);
    gru_gate2<<<KB * KH / 256, 256, 0, stream>>>(PAE, Gh, idxbuf, b_ih, b_hh,
                                                 hbuf, hHi, hLo, j == 0);
    gemm1_head_epi<<<dim3(KA / 128, KB / 128), 256, 0, stream>>>(
        hHi, HwHi, out, head_b, x_, mask, empty, idxbuf,
        vmaxkey + (size_t)j * KB, j, sub0[j], sub1[j]);
    sample_lite<<<KB, 256, 0, stream>>>(out, vmaxkey + (size_t)j * KB, mask,
                                        idxbuf, hbuf, head_w, head_b, j,
                                        sub0[j], sub1[j]);
  }
}

// Round 6
// 1154.105 us; speedup vs baseline: 1.2089x; 1.2089x over previous
//
#include <hip/hip_runtime.h>
#include <cstdint>
#include <cstddef>
#include <math.h>

// AtomSelector: B=4096, A=4096, H=768, L=4.
// R6 = R4 structure (separate lean sample_step; un-fused head GEMM) + the
// algebraic gi removal from R5: gi = P[b] + AE[idx_prev[b]], with
// PAE = [cls; ae_w] @ w_ih^T computed once. Per-step gate GEMM is gh-only.
// PRNG: JAX threefry2x32 partitionable scheme (verified exact since R0).

#define KB 4096
#define KA 4096
#define KH 768
#define KL 4

typedef __attribute__((ext_vector_type(8))) short bf16x8;
typedef __attribute__((ext_vector_type(4))) float f32x4;

__host__ __device__ inline unsigned rotl32(unsigned x, int d) {
  return (x << d) | (x >> (32 - d));
}

// Threefry-2x32, 20 rounds
__host__ __device__ inline void tf2x32(unsigned k0, unsigned k1,
                                       unsigned x0, unsigned x1,
                                       unsigned& o0, unsigned& o1) {
  unsigned ks2 = k0 ^ k1 ^ 0x1BD11BDAu;
  x0 += k0; x1 += k1;
#define TF_R(r) { x0 += x1; x1 = rotl32(x1, (r)); x1 ^= x0; }
  TF_R(13) TF_R(15) TF_R(26) TF_R(6)
  x0 += k1;  x1 += ks2 + 1u;
  TF_R(17) TF_R(29) TF_R(16) TF_R(24)
  x0 += ks2; x1 += k0 + 2u;
  TF_R(13) TF_R(15) TF_R(26) TF_R(6)
  x0 += k0;  x1 += k1 + 3u;
  TF_R(17) TF_R(29) TF_R(16) TF_R(24)
  x0 += k1;  x1 += ks2 + 4u;
  TF_R(13) TF_R(15) TF_R(26) TF_R(6)
  x0 += ks2; x1 += k0 + 5u;
#undef TF_R
  o0 = x0; o1 = x1;
}

__device__ inline ushort f2bf(float f) {
  unsigned u = __float_as_uint(f);
  unsigned r = (u + 0x7fffu + ((u >> 16) & 1u)) >> 16;
  return (ushort)r;
}
__device__ inline float bf2f(ushort h) {
  return __uint_as_float(((unsigned)h) << 16);
}

__device__ inline float gumbel_at(unsigned s0, unsigned s1, unsigned ctr) {
  unsigned o0, o1;
  tf2x32(s0, s1, 0u, ctr, o0, o1);
  unsigned bits = o0 ^ o1;
  float f = __uint_as_float((bits >> 9) | 0x3f800000u) - 1.0f;
  const float TINY = 1.17549435e-38f;
  float u = fmaxf(TINY, f + TINY);
  return -logf(-logf(u));
}

// ---------------------------------------------------------------------------
// gemm3_nt: C[M,N] = A[M,768] @ W[N,768]^T via bf16x2-split MFMA (3 products).
// 256 thr / 4 waves; BM=BN=128, BK=64; wave -> 64x64 (4x4 of 16x16 tiles).
// LDS: 4 planes, global_load_lds width=16, XOR-swizzled chunk slots.
// ---------------------------------------------------------------------------
__global__ __launch_bounds__(256) void gemm3_nt(
    const ushort* __restrict__ Ahi, const ushort* __restrict__ Alo,
    const ushort* __restrict__ Bhi, const ushort* __restrict__ Blo,
    float* __restrict__ C, long long ldc) {
  __shared__ ushort smem[4 * 128 * 64];
  const int tid = threadIdx.x;
  const int wave = tid >> 6;
  const int lane = tid & 63;
  const long long bm = (long long)blockIdx.y * 128;
  const long long bn = (long long)blockIdx.x * 128;
  const int wm = (wave & 1) * 64;
  const int wn = (wave >> 1) * 64;

  f32x4 acc[4][4];
#pragma unroll
  for (int i = 0; i < 4; ++i)
#pragma unroll
    for (int j = 0; j < 4; ++j) acc[i][j] = (f32x4){0.f, 0.f, 0.f, 0.f};

  const int r = lane >> 3;
  const int csrc = (lane & 7) ^ r;
  const int m15 = lane & 15;
  const int kg = (lane >> 4) & 3;

  for (int kt = 0; kt < 12; ++kt) {
    const int k0 = kt * 64;
#pragma unroll
    for (int s = 0; s < 4; ++s) {
      const int m0 = wave * 32 + s * 8;
      const long long arow = (bm + m0 + r) * KH + k0 + csrc * 8;
      const long long brow = (bn + m0 + r) * KH + k0 + csrc * 8;
      __builtin_amdgcn_global_load_lds(
          (const __attribute__((address_space(1))) void*)(Ahi + arow),
          (__attribute__((address_space(3))) void*)&smem[0 * 8192 + m0 * 64], 16, 0, 0);
      __builtin_amdgcn_global_load_lds(
          (const __attribute__((address_space(1))) void*)(Alo + arow),
          (__attribute__((address_space(3))) void*)&smem[1 * 8192 + m0 * 64], 16, 0, 0);
      __builtin_amdgcn_global_load_lds(
          (const __attribute__((address_space(1))) void*)(Bhi + brow),
          (__attribute__((address_space(3))) void*)&smem[2 * 8192 + m0 * 64], 16, 0, 0);
      __builtin_amdgcn_global_load_lds(
          (const __attribute__((address_space(1))) void*)(Blo + brow),
          (__attribute__((address_space(3))) void*)&smem[3 * 8192 + m0 * 64], 16, 0, 0);
    }
    __syncthreads();
#pragma unroll
    for (int ks = 0; ks < 2; ++ks) {
      bf16x8 ah[4], al[4], bh[4], bl[4];
#pragma unroll
      for (int i = 0; i < 4; ++i) {
        const int m = wm + i * 16 + m15;
        const int slot = (ks * 4 + kg) ^ (lane & 7);
        ah[i] = *(const bf16x8*)&smem[0 * 8192 + m * 64 + slot * 8];
        al[i] = *(const bf16x8*)&smem[1 * 8192 + m * 64 + slot * 8];
        const int n = wn + i * 16 + m15;
        bh[i] = *(const bf16x8*)&smem[2 * 8192 + n * 64 + slot * 8];
        bl[i] = *(const bf16x8*)&smem[3 * 8192 + n * 64 + slot * 8];
      }
#pragma unroll
      for (int i = 0; i < 4; ++i)
#pragma unroll
        for (int j = 0; j < 4; ++j) {
          acc[i][j] = __builtin_amdgcn_mfma_f32_16x16x32_bf16(ah[i], bh[j], acc[i][j], 0, 0, 0);
          acc[i][j] = __builtin_amdgcn_mfma_f32_16x16x32_bf16(ah[i], bl[j], acc[i][j], 0, 0, 0);
          acc[i][j] = __builtin_amdgcn_mfma_f32_16x16x32_bf16(al[i], bh[j], acc[i][j], 0, 0, 0);
        }
    }
    __syncthreads();
  }
  const int rq = (lane >> 4) * 4;
#pragma unroll
  for (int i = 0; i < 4; ++i)
#pragma unroll
    for (int j = 0; j < 4; ++j) {
      const long long n = bn + wn + j * 16 + m15;
#pragma unroll
      for (int rg = 0; rg < 4; ++rg) {
        const long long m = bm + wm + i * 16 + rq + rg;
        C[m * ldc + n] = acc[i][j][rg];
      }
    }
}

// ---------------------------------------------------------------------------
// Head GEMM: single-product bf16, no epilogue fusion (R4-proven).
// ---------------------------------------------------------------------------
__global__ __launch_bounds__(256) void gemm1_nt(
    const ushort* __restrict__ Ahi, const ushort* __restrict__ Bhi,
    float* __restrict__ C, long long ldc) {
  __shared__ ushort smem[2 * 128 * 64];
  const int tid = threadIdx.x;
  const int wave = tid >> 6;
  const int lane = tid & 63;
  const long long bm = (long long)blockIdx.y * 128;
  const long long bn = (long long)blockIdx.x * 128;
  const int wm = (wave & 1) * 64;
  const int wn = (wave >> 1) * 64;

  f32x4 acc[4][4];
#pragma unroll
  for (int i = 0; i < 4; ++i)
#pragma unroll
    for (int j = 0; j < 4; ++j) acc[i][j] = (f32x4){0.f, 0.f, 0.f, 0.f};

  const int r = lane >> 3;
  const int csrc = (lane & 7) ^ r;
  const int m15 = lane & 15;
  const int kg = (lane >> 4) & 3;

  for (int kt = 0; kt < 12; ++kt) {
    const int k0 = kt * 64;
#pragma unroll
    for (int s = 0; s < 4; ++s) {
      const int m0 = wave * 32 + s * 8;
      const long long arow = (bm + m0 + r) * KH + k0 + csrc * 8;
      const long long brow = (bn + m0 + r) * KH + k0 + csrc * 8;
      __builtin_amdgcn_global_load_lds(
          (const __attribute__((address_space(1))) void*)(Ahi + arow),
          (__attribute__((address_space(3))) void*)&smem[0 * 8192 + m0 * 64], 16, 0, 0);
      __builtin_amdgcn_global_load_lds(
          (const __attribute__((address_space(1))) void*)(Bhi + brow),
          (__attribute__((address_space(3))) void*)&smem[1 * 8192 + m0 * 64], 16, 0, 0);
    }
    __syncthreads();
#pragma unroll
    for (int ks = 0; ks < 2; ++ks) {
      bf16x8 ah[4], bh[4];
#pragma unroll
      for (int i = 0; i < 4; ++i) {
        const int m = wm + i * 16 + m15;
        const int slot = (ks * 4 + kg) ^ (lane & 7);
        ah[i] = *(const bf16x8*)&smem[0 * 8192 + m * 64 + slot * 8];
        const int n = wn + i * 16 + m15;
        bh[i] = *(const bf16x8*)&smem[1 * 8192 + n * 64 + slot * 8];
      }
#pragma unroll
      for (int i = 0; i < 4; ++i)
#pragma unroll
        for (int j = 0; j < 4; ++j)
          acc[i][j] = __builtin_amdgcn_mfma_f32_16x16x32_bf16(ah[i], bh[j], acc[i][j], 0, 0, 0);
    }
    __syncthreads();
  }
  const int rq = (lane >> 4) * 4;
#pragma unroll
  for (int i = 0; i < 4; ++i)
#pragma unroll
    for (int j = 0; j < 4; ++j) {
      const long long n = bn + wn + j * 16 + m15;
#pragma unroll
      for (int rg = 0; rg < 4; ++rg) {
        const long long m = bm + wm + i * 16 + rq + rg;
        C[m * ldc + n] = acc[i][j][rg];
      }
    }
}

// ---------------------------------------------------------------------------
// Merged preamble: bf16 hi/lo splits of w_ih, w_hh, head_w(hi only),
// [cls; ae_w] -> CAhi/CAlo. One launch.
// ---------------------------------------------------------------------------
#define CUM1 442368   // w_ih  (3*768*768/4)
#define CUM2 884736   // w_hh
#define CUM3 1671168  // head_w (+4096*768/4)
#define CUM4 2457600  // cls
#define CUM5 3244032  // ae_w
#define PREP_CONV_BLOCKS 12672  // CUM5/256

__global__ void prep(const float* __restrict__ w_ih, const float* __restrict__ w_hh,
                     const float* __restrict__ head_w, const float* __restrict__ cls,
                     const float* __restrict__ ae_w,
                     ushort* __restrict__ WihHi, ushort* __restrict__ WihLo,
                     ushort* __restrict__ WhhHi, ushort* __restrict__ WhhLo,
                     ushort* __restrict__ HwHi, ushort* __restrict__ CAhi,
                     ushort* __restrict__ CAlo) {
  const int i = blockIdx.x * 256 + threadIdx.x;
  const float* src; ushort* dhi; ushort* dlo; int base; int split; int ofs = 0;
  if (i < CUM1)      { src = w_ih;   dhi = WihHi; dlo = WihLo; base = 0;    split = 1; }
  else if (i < CUM2) { src = w_hh;   dhi = WhhHi; dlo = WhhLo; base = CUM1; split = 1; }
  else if (i < CUM3) { src = head_w; dhi = HwHi;  dlo = 0;     base = CUM2; split = 0; }
  else if (i < CUM4) { src = cls;    dhi = CAhi;  dlo = CAlo;  base = CUM3; split = 1; }
  else               { src = ae_w;   dhi = CAhi;  dlo = CAlo;  base = CUM4; split = 1; ofs = 786432; }
  const int k = i - base;
  float4 v = ((const float4*)src)[k];
  ushort4 h;
  h.x = f2bf(v.x); h.y = f2bf(v.y); h.z = f2bf(v.z); h.w = f2bf(v.w);
  ((ushort4*)dhi)[ofs + k] = h;
  if (split) {
    ushort4 l;
    l.x = f2bf(v.x - bf2f(h.x)); l.y = f2bf(v.y - bf2f(h.y));
    l.z = f2bf(v.z - bf2f(h.z)); l.w = f2bf(v.w - bf2f(h.w));
    ((ushort4*)dlo)[ofs + k] = l;
  }
}

// GRU gates: gi = P[b] (+ AE[idx_prev[b]] if j>0) + b_ih; gh from Gh (j>0).
__global__ void gru_gate2(const float* __restrict__ PAE, const float* __restrict__ Gh,
                          const int* __restrict__ idxbuf,
                          const float* __restrict__ b_ih, const float* __restrict__ b_hh,
                          float* __restrict__ h, ushort* __restrict__ hHi,
                          ushort* __restrict__ hLo, int first) {
  int i = blockIdx.x * 256 + threadIdx.x;  // over B*H
  int b = i / KH, c = i - b * KH;
  const float* gp = PAE + (size_t)b * (3 * KH);
  float ir = gp[c], iz = gp[c + KH], in_ = gp[c + 2 * KH];
  float hr = b_hh[c], hz = b_hh[c + KH], hn = b_hh[c + 2 * KH];
  float hp = 0.f;
  if (!first) {
    const float* ga = PAE + ((size_t)KB + idxbuf[b]) * (3 * KH);
    ir += ga[c]; iz += ga[c + KH]; in_ += ga[c + 2 * KH];
    const float* gh = Gh + (size_t)b * (3 * KH);
    hr += gh[c]; hz += gh[c + KH]; hn += gh[c + 2 * KH];
    hp = h[i];
  }
  ir += b_ih[c]; iz += b_ih[c + KH]; in_ += b_ih[c + 2 * KH];
  float rr = 1.f / (1.f + expf(-(ir + hr)));
  float z = 1.f / (1.f + expf(-(iz + hz)));
  float n = tanhf(in_ + rr * hn);
  float hv = (1.f - z) * n + z * hp;
  h[i] = hv;
  ushort hh = f2bf(hv);
  hHi[i] = hh;
  hLo[i] = f2bf(hv - bf2f(hh));
}

// One block per batch row (R4-proven): approx vals in registers, single
// max-reduction, eps-window collect, exact fp32 refinement, one-hot write.
__global__ __launch_bounds__(256) void sample_step(
    float* __restrict__ out, const float* __restrict__ head_b,
    const float* __restrict__ x_, unsigned char* __restrict__ mask,
    int* __restrict__ idxbuf, const float* __restrict__ hbuf,
    const float* __restrict__ head_w, int j, unsigned s0, unsigned s1) {
  const int b = blockIdx.x;
  const int tid = threadIdx.x;
  float* orow = out + ((size_t)b * KL + j) * KA;
  unsigned char* mrow = mask + (size_t)b * KA;
  const float* xrow = x_ + (size_t)b * KA;
  __shared__ float sv[256];
  __shared__ int si[256];
  __shared__ int scand[16];
  __shared__ float srefined[16];
  __shared__ int scnt;
  __shared__ int ssel;
  const float EPS = 0.01f;  // >> 2x bf16 logit error bound (~4e-3)

  if (tid == 0) scnt = 0;

  int idx_prev = 0;
  if (j > 0) idx_prev = idxbuf[b];

  int empty = 0;
  if (j == 0) {
    int cnt = 0;
#pragma unroll
    for (int t = 0; t < 16; ++t) cnt += (xrow[tid + (t << 8)] != 0.f) ? 1 : 0;
    si[tid] = cnt;
    __syncthreads();
    for (int s = 128; s > 0; s >>= 1) {
      if (tid < s) si[tid] += si[tid + s];
      __syncthreads();
    }
    empty = (si[0] == 0);
    __syncthreads();
  }

  // Phase 1: approx candidate values into registers.
  float vreg[16];
  unsigned mbits = 0;
  float lmax = -INFINITY;
#pragma unroll
  for (int t = 0; t < 16; ++t) {
    int a = tid + (t << 8);
    int m;
    if (j == 0) {
      m = (xrow[a] != 0.f) ? 1 : 0;
      if (empty && a == 0) m = 1;
    } else {
      m = mrow[a];
      if (idx_prev == 0) m = 0;
      if (a == 0) m = 1;
    }
    float v = -INFINITY;
    if (m) {
      float g = gumbel_at(s0, s1, (unsigned)(b * KA + a));
      v = orow[a] + head_b[a] + g;
      mbits |= (1u << t);
    }
    vreg[t] = v;
    lmax = fmaxf(lmax, v);
  }
  // Phase 2: single block max-reduction.
  sv[tid] = lmax;
  __syncthreads();
  for (int s = 128; s > 0; s >>= 1) {
    if (tid < s) sv[tid] = fmaxf(sv[tid], sv[tid + s]);
    __syncthreads();
  }
  const float vmax = sv[0];

  // Phase 3: collect eps-window candidates (<=16; typically 1).
  const float thresh = vmax - EPS;
#pragma unroll
  for (int t = 0; t < 16; ++t) {
    if (vreg[t] >= thresh) {
      int slot = atomicAdd(&scnt, 1);
      if (slot < 16) scand[slot] = tid + (t << 8);
    }
  }
  __syncthreads();
  const int ncand = min(scnt, 16);

  // Phase 4: exact fp32 refinement; wave w handles candidates w, w+4, ...
  {
    const int wv = tid >> 6;
    const int lane = tid & 63;
    const float4* h4 = (const float4*)(hbuf + (size_t)b * KH);
    for (int t = wv; t < ncand; t += 4) {
      const int a = scand[t];
      const float4* w4 = (const float4*)(head_w + (size_t)a * KH);
      float sum = 0.f;
#pragma unroll
      for (int u = 0; u < 3; ++u) {  // 768/4 = 192 float4 over 64 lanes
        float4 hv = h4[lane + u * 64];
        float4 wv4 = w4[lane + u * 64];
        sum = fmaf(hv.x, wv4.x, sum);
        sum = fmaf(hv.y, wv4.y, sum);
        sum = fmaf(hv.z, wv4.z, sum);
        sum = fmaf(hv.w, wv4.w, sum);
      }
#pragma unroll
      for (int off = 32; off > 0; off >>= 1) sum += __shfl_down(sum, off);
      if (lane == 0) {
        float g = gumbel_at(s0, s1, (unsigned)(b * KA + a));
        srefined[t] = sum + head_b[a] + g;
      }
    }
  }
  __syncthreads();

  // Phase 5: final argmax over refined candidates (lower index on ties).
  if (tid == 0) {
    float best = -INFINITY;
    int bsel = KA;
    for (int t = 0; t < ncand; ++t) {
      float v = srefined[t];
      int a = scand[t];
      if (v > best || (v == best && a < bsel)) { best = v; bsel = a; }
    }
    ssel = bsel;
  }
  __syncthreads();
  const int sel = ssel;

  // Phase 6: one-hot + mask update.
#pragma unroll
  for (int t = 0; t < 16; ++t) {
    int a = tid + (t << 8);
    int m = (mbits >> t) & 1;
    if (a == sel) m = 0;
    mrow[a] = (unsigned char)m;
    orow[a] = (a == sel) ? 1.f : 0.f;
  }
  if (tid == 0) idxbuf[b] = sel;
}

extern "C" void kernel_launch(void* const* d_in, const int* in_sizes, int n_in,
                              void* d_out, int out_size, void* d_ws, size_t ws_size,
                              hipStream_t stream) {
  const float* cls    = (const float*)d_in[0];
  const float* x_     = (const float*)d_in[1];
  const float* w_ih   = (const float*)d_in[2];
  const float* w_hh   = (const float*)d_in[3];
  const float* b_ih   = (const float*)d_in[4];
  const float* b_hh   = (const float*)d_in[5];
  const float* head_w = (const float*)d_in[6];
  const float* head_b = (const float*)d_in[7];
  const float* ae_w   = (const float*)d_in[8];
  float* out = (float*)d_out;

  char* p = (char*)d_ws;
  ushort* CAhi  = (ushort*)p; p += (size_t)2 * KB * KH * 2;     // [cls; ae_w] hi
  ushort* CAlo  = (ushort*)p; p += (size_t)2 * KB * KH * 2;
  ushort* WihHi = (ushort*)p; p += (size_t)3 * KH * KH * 2;
  ushort* WihLo = (ushort*)p; p += (size_t)3 * KH * KH * 2;
  ushort* WhhHi = (ushort*)p; p += (size_t)3 * KH * KH * 2;
  ushort* WhhLo = (ushort*)p; p += (size_t)3 * KH * KH * 2;
  ushort* HwHi  = (ushort*)p; p += (size_t)KA * KH * 2;
  ushort* hHi   = (ushort*)p; p += (size_t)KB * KH * 2;
  ushort* hLo   = (ushort*)p; p += (size_t)KB * KH * 2;
  float*  hbuf  = (float*)p;  p += (size_t)KB * KH * 4;
  float*  PAE   = (float*)p;  p += (size_t)2 * KB * 3 * KH * 4; // P | AE
  float*  Gh    = (float*)p;  p += (size_t)KB * 3 * KH * 4;
  unsigned char* mask = (unsigned char*)p; p += (size_t)KB * KA;
  int* idxbuf = (int*)p; p += (size_t)KB * 4;

  // Host-side JAX key schedule (partitionable split of key(42)).
  unsigned key0 = 0u, key1 = 42u;
  unsigned sub0[KL], sub1[KL];
  for (int j = 0; j < KL; ++j) {
    unsigned n0, n1, t0, t1;
    tf2x32(key0, key1, 0u, 0u, n0, n1);
    tf2x32(key0, key1, 0u, 1u, t0, t1);
    sub0[j] = t0; sub1[j] = t1;
    key0 = n0; key1 = n1;
  }

  // Preamble: all bf16 splits in one launch.
  prep<<<PREP_CONV_BLOCKS, 256, 0, stream>>>(
      w_ih, w_hh, head_w, cls, ae_w,
      WihHi, WihLo, WhhHi, WhhLo, HwHi, CAhi, CAlo);
  // P = cls @ w_ih^T ; AE = ae_w @ w_ih^T  (one concatenated dispatch).
  gemm3_nt<<<dim3(3 * KH / 128, 2 * KB / 128), 256, 0, stream>>>(
      CAhi, CAlo, WihHi, WihLo, PAE, 3 * KH);

  for (int j = 0; j < KL; ++j) {
    if (j > 0)
      gemm3_nt<<<dim3(3 * KH / 128, KB / 128), 256, 0, stream>>>(
          hHi, hLo, WhhHi, WhhLo, Gh, 3 * KH);
    gru_gate2<<<KB * KH / 256, 256, 0, stream>>>(PAE, Gh, idxbuf, b_ih, b_hh,
                                                 hbuf, hHi, hLo, j == 0);
    // approx logits (bf16 single product) straight into d_out[:, j, :]
    gemm1_nt<<<dim3(KA / 128, KB / 128), 256, 0, stream>>>(
        hHi, HwHi, out + (size_t)j * KA, (long long)KL * KA);
    sample_step<<<KB, 256, 0, stream>>>(out, head_b, x_, mask, idxbuf, hbuf,
                                        head_w, j, sub0[j], sub1[j]);
  }
}

// Round 7
// 1054.651 us; speedup vs baseline: 1.3229x; 1.0943x over previous
//
#include <hip/hip_runtime.h>
#include <cstdint>
#include <cstddef>
#include <math.h>

// AtomSelector: B=4096, A=4096, H=768, L=4.
// R7 = R6 + occupancy fix: gemm3 BK=32 (32 KB LDS -> 3 blocks/CU; gh's 576
// blocks fit one round), gemm1 BK=32 (16 KB), resident-B/streamed-A fragment
// loop (lower VGPR), vectorized sample_step/gru_gate2, empty[] in prep.
// PRNG: JAX threefry2x32 partitionable scheme (verified exact since R0).

#define KB 4096
#define KA 4096
#define KH 768
#define KL 4

typedef __attribute__((ext_vector_type(8))) short bf16x8;
typedef __attribute__((ext_vector_type(4))) float f32x4;

__host__ __device__ inline unsigned rotl32(unsigned x, int d) {
  return (x << d) | (x >> (32 - d));
}

// Threefry-2x32, 20 rounds
__host__ __device__ inline void tf2x32(unsigned k0, unsigned k1,
                                       unsigned x0, unsigned x1,
                                       unsigned& o0, unsigned& o1) {
  unsigned ks2 = k0 ^ k1 ^ 0x1BD11BDAu;
  x0 += k0; x1 += k1;
#define TF_R(r) { x0 += x1; x1 = rotl32(x1, (r)); x1 ^= x0; }
  TF_R(13) TF_R(15) TF_R(26) TF_R(6)
  x0 += k1;  x1 += ks2 + 1u;
  TF_R(17) TF_R(29) TF_R(16) TF_R(24)
  x0 += ks2; x1 += k0 + 2u;
  TF_R(13) TF_R(15) TF_R(26) TF_R(6)
  x0 += k0;  x1 += k1 + 3u;
  TF_R(17) TF_R(29) TF_R(16) TF_R(24)
  x0 += k1;  x1 += ks2 + 4u;
  TF_R(13) TF_R(15) TF_R(26) TF_R(6)
  x0 += ks2; x1 += k0 + 5u;
#undef TF_R
  o0 = x0; o1 = x1;
}

__device__ inline ushort f2bf(float f) {
  unsigned u = __float_as_uint(f);
  unsigned r = (u + 0x7fffu + ((u >> 16) & 1u)) >> 16;
  return (ushort)r;
}
__device__ inline float bf2f(ushort h) {
  return __uint_as_float(((unsigned)h) << 16);
}

__device__ inline float gumbel_at(unsigned s0, unsigned s1, unsigned ctr) {
  unsigned o0, o1;
  tf2x32(s0, s1, 0u, ctr, o0, o1);
  unsigned bits = o0 ^ o1;
  float f = __uint_as_float((bits >> 9) | 0x3f800000u) - 1.0f;
  const float TINY = 1.17549435e-38f;
  float u = fmaxf(TINY, f + TINY);
  return -logf(-logf(u));
}

#define GLDS(gp, lp) \
  __builtin_amdgcn_global_load_lds( \
      (const __attribute__((address_space(1))) void*)(gp), \
      (__attribute__((address_space(3))) void*)(lp), 16, 0, 0)

// ---------------------------------------------------------------------------
// gemm3_nt: C[M,N] = A[M,768] @ W[N,768]^T, bf16x2 split, 3 MFMA products.
// BK=32 -> 4 planes x 128x32 bf16 = 32 KB LDS -> 3 blocks/CU.
// Staging: per issue 16 rows x 4 chunks, lane r=lane>>2, cs=lane&3,
// source chunk csrc = cs ^ f(r), f(r) = (r&3)^((r>>2)&3).
// Compute: slot = kg ^ f(m15); per-(parity,slot) pairs occur exactly 2x
// -> only free 2-way LDS aliasing.
// ---------------------------------------------------------------------------
__global__ __launch_bounds__(256) void gemm3_nt(
    const ushort* __restrict__ Ahi, const ushort* __restrict__ Alo,
    const ushort* __restrict__ Bhi, const ushort* __restrict__ Blo,
    float* __restrict__ C, long long ldc) {
  __shared__ ushort smem[4 * 128 * 32];  // 32 KB
  const int tid = threadIdx.x;
  const int wave = tid >> 6;
  const int lane = tid & 63;
  const long long bm = (long long)blockIdx.y * 128;
  const long long bn = (long long)blockIdx.x * 128;
  const int wm = (wave & 1) * 64;
  const int wn = (wave >> 1) * 64;

  f32x4 acc[4][4];
#pragma unroll
  for (int i = 0; i < 4; ++i)
#pragma unroll
    for (int j = 0; j < 4; ++j) acc[i][j] = (f32x4){0.f, 0.f, 0.f, 0.f};

  const int r = lane >> 2;
  const int cs = lane & 3;
  const int csrc = cs ^ ((r & 3) ^ ((r >> 2) & 3));
  const int m15 = lane & 15;
  const int kg = (lane >> 4) & 3;
  const int slot = kg ^ ((m15 & 3) ^ ((m15 >> 2) & 3));

  for (int kt = 0; kt < 24; ++kt) {
    const int k0 = kt * 32;
#pragma unroll
    for (int s = 0; s < 2; ++s) {
      const int m0 = wave * 32 + s * 16;
      const long long arow = (bm + m0 + r) * KH + k0 + csrc * 8;
      const long long brow = (bn + m0 + r) * KH + k0 + csrc * 8;
      GLDS(Ahi + arow, &smem[0 * 4096 + m0 * 32]);
      GLDS(Alo + arow, &smem[1 * 4096 + m0 * 32]);
      GLDS(Bhi + brow, &smem[2 * 4096 + m0 * 32]);
      GLDS(Blo + brow, &smem[3 * 4096 + m0 * 32]);
    }
    __syncthreads();
    bf16x8 bh[4], bl[4];
#pragma unroll
    for (int jj = 0; jj < 4; ++jj) {
      const int n = wn + jj * 16 + m15;
      bh[jj] = *(const bf16x8*)&smem[2 * 4096 + n * 32 + slot * 8];
      bl[jj] = *(const bf16x8*)&smem[3 * 4096 + n * 32 + slot * 8];
    }
#pragma unroll
    for (int i = 0; i < 4; ++i) {
      const int m = wm + i * 16 + m15;
      bf16x8 ah = *(const bf16x8*)&smem[0 * 4096 + m * 32 + slot * 8];
      bf16x8 al = *(const bf16x8*)&smem[1 * 4096 + m * 32 + slot * 8];
#pragma unroll
      for (int jj = 0; jj < 4; ++jj) {
        acc[i][jj] = __builtin_amdgcn_mfma_f32_16x16x32_bf16(ah, bh[jj], acc[i][jj], 0, 0, 0);
        acc[i][jj] = __builtin_amdgcn_mfma_f32_16x16x32_bf16(ah, bl[jj], acc[i][jj], 0, 0, 0);
        acc[i][jj] = __builtin_amdgcn_mfma_f32_16x16x32_bf16(al, bh[jj], acc[i][jj], 0, 0, 0);
      }
    }
    __syncthreads();
  }
  const int rq = (lane >> 4) * 4;
#pragma unroll
  for (int i = 0; i < 4; ++i)
#pragma unroll
    for (int j = 0; j < 4; ++j) {
      const long long n = bn + wn + j * 16 + m15;
#pragma unroll
      for (int rg = 0; rg < 4; ++rg) {
        const long long m = bm + wm + i * 16 + rq + rg;
        C[m * ldc + n] = acc[i][j][rg];
      }
    }
}

// ---------------------------------------------------------------------------
// Head GEMM: single-product bf16, BK=32 -> 2 planes = 16 KB LDS.
// ---------------------------------------------------------------------------
__global__ __launch_bounds__(256) void gemm1_nt(
    const ushort* __restrict__ Ahi, const ushort* __restrict__ Bhi,
    float* __restrict__ C, long long ldc) {
  __shared__ ushort smem[2 * 128 * 32];  // 16 KB
  const int tid = threadIdx.x;
  const int wave = tid >> 6;
  const int lane = tid & 63;
  const long long bm = (long long)blockIdx.y * 128;
  const long long bn = (long long)blockIdx.x * 128;
  const int wm = (wave & 1) * 64;
  const int wn = (wave >> 1) * 64;

  f32x4 acc[4][4];
#pragma unroll
  for (int i = 0; i < 4; ++i)
#pragma unroll
    for (int j = 0; j < 4; ++j) acc[i][j] = (f32x4){0.f, 0.f, 0.f, 0.f};

  const int r = lane >> 2;
  const int cs = lane & 3;
  const int csrc = cs ^ ((r & 3) ^ ((r >> 2) & 3));
  const int m15 = lane & 15;
  const int kg = (lane >> 4) & 3;
  const int slot = kg ^ ((m15 & 3) ^ ((m15 >> 2) & 3));

  for (int kt = 0; kt < 24; ++kt) {
    const int k0 = kt * 32;
#pragma unroll
    for (int s = 0; s < 2; ++s) {
      const int m0 = wave * 32 + s * 16;
      const long long arow = (bm + m0 + r) * KH + k0 + csrc * 8;
      const long long brow = (bn + m0 + r) * KH + k0 + csrc * 8;
      GLDS(Ahi + arow, &smem[0 * 4096 + m0 * 32]);
      GLDS(Bhi + brow, &smem[1 * 4096 + m0 * 32]);
    }
    __syncthreads();
    bf16x8 bh[4];
#pragma unroll
    for (int jj = 0; jj < 4; ++jj) {
      const int n = wn + jj * 16 + m15;
      bh[jj] = *(const bf16x8*)&smem[1 * 4096 + n * 32 + slot * 8];
    }
#pragma unroll
    for (int i = 0; i < 4; ++i) {
      const int m = wm + i * 16 + m15;
      bf16x8 ah = *(const bf16x8*)&smem[0 * 4096 + m * 32 + slot * 8];
#pragma unroll
      for (int jj = 0; jj < 4; ++jj)
        acc[i][jj] = __builtin_amdgcn_mfma_f32_16x16x32_bf16(ah, bh[jj], acc[i][jj], 0, 0, 0);
    }
    __syncthreads();
  }
  const int rq = (lane >> 4) * 4;
#pragma unroll
  for (int i = 0; i < 4; ++i)
#pragma unroll
    for (int j = 0; j < 4; ++j) {
      const long long n = bn + wn + j * 16 + m15;
#pragma unroll
      for (int rg = 0; rg < 4; ++rg) {
        const long long m = bm + wm + i * 16 + rq + rg;
        C[m * ldc + n] = acc[i][j][rg];
      }
    }
}

// ---------------------------------------------------------------------------
// Merged preamble: bf16 hi/lo splits + empty[] rows of x_.
// ---------------------------------------------------------------------------
#define CUM1 442368   // w_ih  (3*768*768/4)
#define CUM2 884736   // w_hh
#define CUM3 1671168  // head_w (+4096*768/4)
#define CUM4 2457600  // cls
#define CUM5 3244032  // ae_w
#define PREP_CONV_BLOCKS 12672  // CUM5/256

__global__ void prep(const float* __restrict__ w_ih, const float* __restrict__ w_hh,
                     const float* __restrict__ head_w, const float* __restrict__ cls,
                     const float* __restrict__ ae_w, const float* __restrict__ x_,
                     ushort* __restrict__ WihHi, ushort* __restrict__ WihLo,
                     ushort* __restrict__ WhhHi, ushort* __restrict__ WhhLo,
                     ushort* __restrict__ HwHi, ushort* __restrict__ CAhi,
                     ushort* __restrict__ CAlo, unsigned char* __restrict__ empty) {
  const int blk = blockIdx.x;
  const int tid = threadIdx.x;
  if (blk < PREP_CONV_BLOCKS) {
    const int i = blk * 256 + tid;
    const float* src; ushort* dhi; ushort* dlo; int base; int split; int ofs = 0;
    if (i < CUM1)      { src = w_ih;   dhi = WihHi; dlo = WihLo; base = 0;    split = 1; }
    else if (i < CUM2) { src = w_hh;   dhi = WhhHi; dlo = WhhLo; base = CUM1; split = 1; }
    else if (i < CUM3) { src = head_w; dhi = HwHi;  dlo = 0;     base = CUM2; split = 0; }
    else if (i < CUM4) { src = cls;    dhi = CAhi;  dlo = CAlo;  base = CUM3; split = 1; }
    else               { src = ae_w;   dhi = CAhi;  dlo = CAlo;  base = CUM4; split = 1; ofs = 786432; }
    const int k = i - base;
    float4 v = ((const float4*)src)[k];
    ushort4 h;
    h.x = f2bf(v.x); h.y = f2bf(v.y); h.z = f2bf(v.z); h.w = f2bf(v.w);
    ((ushort4*)dhi)[ofs + k] = h;
    if (split) {
      ushort4 l;
      l.x = f2bf(v.x - bf2f(h.x)); l.y = f2bf(v.y - bf2f(h.y));
      l.z = f2bf(v.z - bf2f(h.z)); l.w = f2bf(v.w - bf2f(h.w));
      ((ushort4*)dlo)[ofs + k] = l;
    }
  } else {
    const int row = blk - PREP_CONV_BLOCKS;  // 0..4095
    __shared__ int scnt[256];
    const float4* xr = (const float4*)(x_ + (size_t)row * KA);
    int cnt = 0;
#pragma unroll
    for (int k = 0; k < 4; ++k) {
      float4 v = xr[tid + (k << 8)];
      cnt += (v.x != 0.f) + (v.y != 0.f) + (v.z != 0.f) + (v.w != 0.f);
    }
    scnt[tid] = cnt;
    __syncthreads();
    for (int s = 128; s > 0; s >>= 1) {
      if (tid < s) scnt[tid] += scnt[tid + s];
      __syncthreads();
    }
    if (tid == 0) empty[row] = (scnt[0] == 0) ? 1 : 0;
  }
}

// GRU gates (f32x4 vectorized): gi = P[b] (+ AE[idx_prev[b]]) + b_ih;
// gh from Gh GEMM (j>0). h fp32 + bf16 hi/lo planes written.
__global__ void gru_gate2(const float* __restrict__ PAE, const float* __restrict__ Gh,
                          const int* __restrict__ idxbuf,
                          const float* __restrict__ b_ih, const float* __restrict__ b_hh,
                          float* __restrict__ h, ushort* __restrict__ hHi,
                          ushort* __restrict__ hLo, int first) {
  int i4 = blockIdx.x * 256 + threadIdx.x;  // over B*KH/4
  int b = i4 / (KH / 4);
  int c4 = i4 - b * (KH / 4);
  const f32x4* gp = (const f32x4*)(PAE + (size_t)b * (3 * KH));
  f32x4 ir = gp[c4], iz = gp[c4 + 192], inn = gp[c4 + 384];
  const f32x4* bi = (const f32x4*)b_ih;
  const f32x4* bhh = (const f32x4*)b_hh;
  f32x4 hr = bhh[c4], hz = bhh[c4 + 192], hn = bhh[c4 + 384];
  f32x4 hp = (f32x4){0.f, 0.f, 0.f, 0.f};
  if (!first) {
    const f32x4* ga = (const f32x4*)(PAE + ((size_t)KB + idxbuf[b]) * (3 * KH));
    ir += ga[c4]; iz += ga[c4 + 192]; inn += ga[c4 + 384];
    const f32x4* gh = (const f32x4*)(Gh + (size_t)b * (3 * KH));
    hr += gh[c4]; hz += gh[c4 + 192]; hn += gh[c4 + 384];
    hp = ((const f32x4*)h)[i4];
  }
  ir += bi[c4]; iz += bi[c4 + 192]; inn += bi[c4 + 384];
  f32x4 hv;
  ushort4 hh, hl;
  ushort* hhp = &hh.x;
  ushort* hlp = &hl.x;
#pragma unroll
  for (int e = 0; e < 4; ++e) {
    float rr = 1.f / (1.f + expf(-(ir[e] + hr[e])));
    float z = 1.f / (1.f + expf(-(iz[e] + hz[e])));
    float n = tanhf(inn[e] + rr * hn[e]);
    float v = (1.f - z) * n + z * hp[e];
    hv[e] = v;
    ushort hb = f2bf(v);
    hhp[e] = hb;
    hlp[e] = f2bf(v - bf2f(hb));
  }
  ((f32x4*)h)[i4] = hv;
  ((ushort4*)hHi)[i4] = hh;
  ((ushort4*)hLo)[i4] = hl;
}

// One block per batch row: approx vals (float4 IO) in registers, single
// max-reduction, eps-window collect, exact fp32 refinement, one-hot write.
__global__ __launch_bounds__(256) void sample_step(
    float* __restrict__ out, const float* __restrict__ head_b,
    const float* __restrict__ x_, unsigned char* __restrict__ mask,
    int* __restrict__ idxbuf, const float* __restrict__ hbuf,
    const float* __restrict__ head_w, const unsigned char* __restrict__ empty,
    int j, unsigned s0, unsigned s1) {
  const int b = blockIdx.x;
  const int tid = threadIdx.x;
  float* orow = out + ((size_t)b * KL + j) * KA;
  unsigned char* mrow = mask + (size_t)b * KA;
  const float* xrow = x_ + (size_t)b * KA;
  __shared__ float sv[256];
  __shared__ int scand[16];
  __shared__ float srefined[16];
  __shared__ int scnt;
  __shared__ int ssel;
  const float EPS = 0.01f;  // >> 2x bf16 logit error bound (~4e-3)

  if (tid == 0) scnt = 0;

  const int idx_prev = (j > 0) ? idxbuf[b] : 0;
  const int emp = (j == 0) ? empty[b] : 0;

  // Phase 1: approx candidate values into registers (float4 IO).
  float vreg[16];
  unsigned mbits = 0;
  float lmax = -INFINITY;
  const float4* orow4 = (const float4*)orow;
  const float4* xrow4 = (const float4*)xrow;
  const unsigned* mrow4 = (const unsigned*)mrow;
  const float4* hb4 = (const float4*)head_b;
#pragma unroll
  for (int k = 0; k < 4; ++k) {
    const int ci = tid + (k << 8);
    const int abase = ci * 4;
    float4 lv = orow4[ci];
    float4 hbv = hb4[ci];
    float lvv[4] = {lv.x + hbv.x, lv.y + hbv.y, lv.z + hbv.z, lv.w + hbv.w};
    float xvv[4] = {0.f, 0.f, 0.f, 0.f};
    unsigned mword = 0;
    if (j == 0) {
      float4 xv = xrow4[ci];
      xvv[0] = xv.x; xvv[1] = xv.y; xvv[2] = xv.z; xvv[3] = xv.w;
    } else {
      mword = mrow4[ci];
    }
#pragma unroll
    for (int e = 0; e < 4; ++e) {
      const int a = abase + e;
      int m;
      if (j == 0) {
        m = (xvv[e] != 0.f) || (emp && a == 0);
      } else {
        m = (a == 0) || (idx_prev != 0 && ((mword >> (8 * e)) & 0xffu));
      }
      float v = -INFINITY;
      if (m) {
        float g = gumbel_at(s0, s1, (unsigned)(b * KA + a));
        v = lvv[e] + g;
        mbits |= (1u << (k * 4 + e));
      }
      vreg[k * 4 + e] = v;
      lmax = fmaxf(lmax, v);
    }
  }
  // Phase 2: single block max-reduction.
  sv[tid] = lmax;
  __syncthreads();
  for (int s = 128; s > 0; s >>= 1) {
    if (tid < s) sv[tid] = fmaxf(sv[tid], sv[tid + s]);
    __syncthreads();
  }
  const float vmax = sv[0];

  // Phase 3: collect eps-window candidates (<=16; typically 1).
  const float thresh = vmax - EPS;
#pragma unroll
  for (int k = 0; k < 4; ++k)
#pragma unroll
    for (int e = 0; e < 4; ++e) {
      if (vreg[k * 4 + e] >= thresh) {
        int slot = atomicAdd(&scnt, 1);
        if (slot < 16) scand[slot] = (tid + (k << 8)) * 4 + e;
      }
    }
  __syncthreads();
  const int ncand = min(scnt, 16);

  // Phase 4: exact fp32 refinement; wave w handles candidates w, w+4, ...
  {
    const int wv = tid >> 6;
    const int lane = tid & 63;
    const float4* h4 = (const float4*)(hbuf + (size_t)b * KH);
    for (int t = wv; t < ncand; t += 4) {
      const int a = scand[t];
      const float4* w4 = (const float4*)(head_w + (size_t)a * KH);
      float sum = 0.f;
#pragma unroll
      for (int u = 0; u < 3; ++u) {  // 768/4 = 192 float4 over 64 lanes
        float4 hv = h4[lane + u * 64];
        float4 wv4 = w4[lane + u * 64];
        sum = fmaf(hv.x, wv4.x, sum);
        sum = fmaf(hv.y, wv4.y, sum);
        sum = fmaf(hv.z, wv4.z, sum);
        sum = fmaf(hv.w, wv4.w, sum);
      }
#pragma unroll
      for (int off = 32; off > 0; off >>= 1) sum += __shfl_down(sum, off);
      if (lane == 0) {
        float g = gumbel_at(s0, s1, (unsigned)(b * KA + a));
        srefined[t] = sum + head_b[a] + g;
      }
    }
  }
  __syncthreads();

  // Phase 5: final argmax over refined candidates (lower index on ties).
  if (tid == 0) {
    float best = -INFINITY;
    int bsel = KA;
    for (int t = 0; t < ncand; ++t) {
      float v = srefined[t];
      int a = scand[t];
      if (v > best || (v == best && a < bsel)) { best = v; bsel = a; }
    }
    ssel = bsel;
  }
  __syncthreads();
  const int sel = ssel;

  // Phase 6: one-hot + mask update (vectorized stores).
#pragma unroll
  for (int k = 0; k < 4; ++k) {
    const int ci = tid + (k << 8);
    const int abase = ci * 4;
    unsigned mw = 0;
    float4 ov;
    float* ovp = &ov.x;
#pragma unroll
    for (int e = 0; e < 4; ++e) {
      const int a = abase + e;
      int m = (mbits >> (k * 4 + e)) & 1;
      if (a == sel) m = 0;
      mw |= ((unsigned)m) << (8 * e);
      ovp[e] = (a == sel) ? 1.f : 0.f;
    }
    ((unsigned*)mrow)[ci] = mw;
    ((float4*)orow)[ci] = ov;
  }
  if (tid == 0) idxbuf[b] = sel;
}

extern "C" void kernel_launch(void* const* d_in, const int* in_sizes, int n_in,
                              void* d_out, int out_size, void* d_ws, size_t ws_size,
                              hipStream_t stream) {
  const float* cls    = (const float*)d_in[0];
  const float* x_     = (const float*)d_in[1];
  const float* w_ih   = (const float*)d_in[2];
  const float* w_hh   = (const float*)d_in[3];
  const float* b_ih   = (const float*)d_in[4];
  const float* b_hh   = (const float*)d_in[5];
  const float* head_w = (const float*)d_in[6];
  const float* head_b = (const float*)d_in[7];
  const float* ae_w   = (const float*)d_in[8];
  float* out = (float*)d_out;

  char* p = (char*)d_ws;
  ushort* CAhi  = (ushort*)p; p += (size_t)2 * KB * KH * 2;     // [cls; ae_w] hi
  ushort* CAlo  = (ushort*)p; p += (size_t)2 * KB * KH * 2;
  ushort* WihHi = (ushort*)p; p += (size_t)3 * KH * KH * 2;
  ushort* WihLo = (ushort*)p; p += (size_t)3 * KH * KH * 2;
  ushort* WhhHi = (ushort*)p; p += (size_t)3 * KH * KH * 2;
  ushort* WhhLo = (ushort*)p; p += (size_t)3 * KH * KH * 2;
  ushort* HwHi  = (ushort*)p; p += (size_t)KA * KH * 2;
  ushort* hHi   = (ushort*)p; p += (size_t)KB * KH * 2;
  ushort* hLo   = (ushort*)p; p += (size_t)KB * KH * 2;
  float*  hbuf  = (float*)p;  p += (size_t)KB * KH * 4;
  float*  PAE   = (float*)p;  p += (size_t)2 * KB * 3 * KH * 4; // P | AE
  float*  Gh    = (float*)p;  p += (size_t)KB * 3 * KH * 4;
  unsigned char* mask  = (unsigned char*)p; p += (size_t)KB * KA;
  unsigned char* empty = (unsigned char*)p; p += (size_t)KB;
  int* idxbuf = (int*)p; p += (size_t)KB * 4;

  // Host-side JAX key schedule (partitionable split of key(42)).
  unsigned key0 = 0u, key1 = 42u;
  unsigned sub0[KL], sub1[KL];
  for (int j = 0; j < KL; ++j) {
    unsigned n0, n1, t0, t1;
    tf2x32(key0, key1, 0u, 0u, n0, n1);
    tf2x32(key0, key1, 0u, 1u, t0, t1);
    sub0[j] = t0; sub1[j] = t1;
    key0 = n0; key1 = n1;
  }

  // Preamble: all bf16 splits + empty[] in one launch.
  prep<<<PREP_CONV_BLOCKS + KB, 256, 0, stream>>>(
      w_ih, w_hh, head_w, cls, ae_w, x_,
      WihHi, WihLo, WhhHi, WhhLo, HwHi, CAhi, CAlo, empty);
  // P = cls @ w_ih^T ; AE = ae_w @ w_ih^T  (one concatenated dispatch).
  gemm3_nt<<<dim3(3 * KH / 128, 2 * KB / 128), 256, 0, stream>>>(
      CAhi, CAlo, WihHi, WihLo, PAE, 3 * KH);

  for (int j = 0; j < KL; ++j) {
    if (j > 0)
      gemm3_nt<<<dim3(3 * KH / 128, KB / 128), 256, 0, stream>>>(
          hHi, hLo, WhhHi, WhhLo, Gh, 3 * KH);
    gru_gate2<<<KB * KH / 4 / 256, 256, 0, stream>>>(PAE, Gh, idxbuf, b_ih, b_hh,
                                                     hbuf, hHi, hLo, j == 0);
    // approx logits (bf16 single product) straight into d_out[:, j, :]
    gemm1_nt<<<dim3(KA / 128, KB / 128), 256, 0, stream>>>(
        hHi, HwHi, out + (size_t)j * KA, (long long)KL * KA);
    sample_step<<<KB, 256, 0, stream>>>(out, head_b, x_, mask, idxbuf, hbuf,
                                        head_w, empty, j, sub0[j], sub1[j]);
  }
}

// Round 8
// 1028.981 us; speedup vs baseline: 1.3559x; 1.0249x over previous
//
#include <hip/hip_runtime.h>
#include <cstdint>
#include <cstddef>
#include <math.h>

// AtomSelector: B=4096, A=4096, H=768, L=4.
// R8 = R7 + (1) fused dispatch: gh GEMM for step j+1 (3-product, depends only
// on h_j) + head GEMM for step j (1-product) in one 1600-block kernel;
// (2) head logits stored as bf16 (v = logit + head_b) in ws Vbuf instead of
// fp32 d_out round-trip; EPS 0.01 -> 0.02 to cover bf16 storage rounding.
// PRNG: JAX threefry2x32 partitionable scheme (verified exact since R0).

#define KB 4096
#define KA 4096
#define KH 768
#define KL 4

typedef __attribute__((ext_vector_type(8))) short bf16x8;
typedef __attribute__((ext_vector_type(4))) float f32x4;

__host__ __device__ inline unsigned rotl32(unsigned x, int d) {
  return (x << d) | (x >> (32 - d));
}

// Threefry-2x32, 20 rounds
__host__ __device__ inline void tf2x32(unsigned k0, unsigned k1,
                                       unsigned x0, unsigned x1,
                                       unsigned& o0, unsigned& o1) {
  unsigned ks2 = k0 ^ k1 ^ 0x1BD11BDAu;
  x0 += k0; x1 += k1;
#define TF_R(r) { x0 += x1; x1 = rotl32(x1, (r)); x1 ^= x0; }
  TF_R(13) TF_R(15) TF_R(26) TF_R(6)
  x0 += k1;  x1 += ks2 + 1u;
  TF_R(17) TF_R(29) TF_R(16) TF_R(24)
  x0 += ks2; x1 += k0 + 2u;
  TF_R(13) TF_R(15) TF_R(26) TF_R(6)
  x0 += k0;  x1 += k1 + 3u;
  TF_R(17) TF_R(29) TF_R(16) TF_R(24)
  x0 += k1;  x1 += ks2 + 4u;
  TF_R(13) TF_R(15) TF_R(26) TF_R(6)
  x0 += ks2; x1 += k0 + 5u;
#undef TF_R
  o0 = x0; o1 = x1;
}

__device__ inline ushort f2bf(float f) {
  unsigned u = __float_as_uint(f);
  unsigned r = (u + 0x7fffu + ((u >> 16) & 1u)) >> 16;
  return (ushort)r;
}
__device__ inline float bf2f(ushort h) {
  return __uint_as_float(((unsigned)h) << 16);
}

__device__ inline float gumbel_at(unsigned s0, unsigned s1, unsigned ctr) {
  unsigned o0, o1;
  tf2x32(s0, s1, 0u, ctr, o0, o1);
  unsigned bits = o0 ^ o1;
  float f = __uint_as_float((bits >> 9) | 0x3f800000u) - 1.0f;
  const float TINY = 1.17549435e-38f;
  float u = fmaxf(TINY, f + TINY);
  return -logf(-logf(u));
}

#define GLDS(gp, lp) \
  __builtin_amdgcn_global_load_lds( \
      (const __attribute__((address_space(1))) void*)(gp), \
      (__attribute__((address_space(3))) void*)(lp), 16, 0, 0)

// ---------------------------------------------------------------------------
// gemm3_nt: C[M,N] = A[M,768] @ W[N,768]^T, bf16x2 split, 3 MFMA products.
// BK=32 -> 32 KB LDS -> 3 blocks/CU. XOR-swizzled chunk slots (R7-proven).
// Used once for PAE = [cls; ae_w] @ w_ih^T.
// ---------------------------------------------------------------------------
__global__ __launch_bounds__(256) void gemm3_nt(
    const ushort* __restrict__ Ahi, const ushort* __restrict__ Alo,
    const ushort* __restrict__ Bhi, const ushort* __restrict__ Blo,
    float* __restrict__ C, long long ldc) {
  __shared__ ushort smem[4 * 128 * 32];  // 32 KB
  const int tid = threadIdx.x;
  const int wave = tid >> 6;
  const int lane = tid & 63;
  const long long bm = (long long)blockIdx.y * 128;
  const long long bn = (long long)blockIdx.x * 128;
  const int wm = (wave & 1) * 64;
  const int wn = (wave >> 1) * 64;

  f32x4 acc[4][4];
#pragma unroll
  for (int i = 0; i < 4; ++i)
#pragma unroll
    for (int j = 0; j < 4; ++j) acc[i][j] = (f32x4){0.f, 0.f, 0.f, 0.f};

  const int r = lane >> 2;
  const int cs = lane & 3;
  const int csrc = cs ^ ((r & 3) ^ ((r >> 2) & 3));
  const int m15 = lane & 15;
  const int kg = (lane >> 4) & 3;
  const int slot = kg ^ ((m15 & 3) ^ ((m15 >> 2) & 3));

  for (int kt = 0; kt < 24; ++kt) {
    const int k0 = kt * 32;
#pragma unroll
    for (int s = 0; s < 2; ++s) {
      const int m0 = wave * 32 + s * 16;
      const long long arow = (bm + m0 + r) * KH + k0 + csrc * 8;
      const long long brow = (bn + m0 + r) * KH + k0 + csrc * 8;
      GLDS(Ahi + arow, &smem[0 * 4096 + m0 * 32]);
      GLDS(Alo + arow, &smem[1 * 4096 + m0 * 32]);
      GLDS(Bhi + brow, &smem[2 * 4096 + m0 * 32]);
      GLDS(Blo + brow, &smem[3 * 4096 + m0 * 32]);
    }
    __syncthreads();
    bf16x8 bh[4], bl[4];
#pragma unroll
    for (int jj = 0; jj < 4; ++jj) {
      const int n = wn + jj * 16 + m15;
      bh[jj] = *(const bf16x8*)&smem[2 * 4096 + n * 32 + slot * 8];
      bl[jj] = *(const bf16x8*)&smem[3 * 4096 + n * 32 + slot * 8];
    }
#pragma unroll
    for (int i = 0; i < 4; ++i) {
      const int m = wm + i * 16 + m15;
      bf16x8 ah = *(const bf16x8*)&smem[0 * 4096 + m * 32 + slot * 8];
      bf16x8 al = *(const bf16x8*)&smem[1 * 4096 + m * 32 + slot * 8];
#pragma unroll
      for (int jj = 0; jj < 4; ++jj) {
        acc[i][jj] = __builtin_amdgcn_mfma_f32_16x16x32_bf16(ah, bh[jj], acc[i][jj], 0, 0, 0);
        acc[i][jj] = __builtin_amdgcn_mfma_f32_16x16x32_bf16(ah, bl[jj], acc[i][jj], 0, 0, 0);
        acc[i][jj] = __builtin_amdgcn_mfma_f32_16x16x32_bf16(al, bh[jj], acc[i][jj], 0, 0, 0);
      }
    }
    __syncthreads();
  }
  const int rq = (lane >> 4) * 4;
#pragma unroll
  for (int i = 0; i < 4; ++i)
#pragma unroll
    for (int j = 0; j < 4; ++j) {
      const long long n = bn + wn + j * 16 + m15;
#pragma unroll
      for (int rg = 0; rg < 4; ++rg) {
        const long long m = bm + wm + i * 16 + rq + rg;
        C[m * ldc + n] = acc[i][j][rg];
      }
    }
}

// ---------------------------------------------------------------------------
// Fused per-step GEMM dispatch:
//   blocks [0, gh_nb)        : Gh_{j+1} = h_j @ w_hh^T   (bf16x2, 3 products)
//   blocks [gh_nb, gh_nb+1024): Vbuf = bf16(h_j @ head_w^T + head_b) (1 prod)
// Both consume h_j only. gh_nb = 576 for j<3, 0 for j==3.
// ---------------------------------------------------------------------------
__global__ __launch_bounds__(256) void gemm_fused(
    const ushort* __restrict__ hHi, const ushort* __restrict__ hLo,
    const ushort* __restrict__ WhhHi, const ushort* __restrict__ WhhLo,
    float* __restrict__ Gh, const ushort* __restrict__ HwHi,
    const float* __restrict__ head_b, ushort* __restrict__ Vbuf, int gh_nb) {
  __shared__ ushort smem[4 * 128 * 32];  // 32 KB (head path uses 2 planes)
  const int tid = threadIdx.x;
  const int wave = tid >> 6;
  const int lane = tid & 63;
  const int bid = blockIdx.x;
  const int wm = (wave & 1) * 64;
  const int wn = (wave >> 1) * 64;
  const int r = lane >> 2;
  const int cs = lane & 3;
  const int csrc = cs ^ ((r & 3) ^ ((r >> 2) & 3));
  const int m15 = lane & 15;
  const int kg = (lane >> 4) & 3;
  const int slot = kg ^ ((m15 & 3) ^ ((m15 >> 2) & 3));

  f32x4 acc[4][4];
#pragma unroll
  for (int i = 0; i < 4; ++i)
#pragma unroll
    for (int j = 0; j < 4; ++j) acc[i][j] = (f32x4){0.f, 0.f, 0.f, 0.f};

  if (bid < gh_nb) {
    // ---- gh path (3-product) ----
    const long long bm = (long long)(bid / 18) * 128;
    const long long bn = (long long)(bid % 18) * 128;
    for (int kt = 0; kt < 24; ++kt) {
      const int k0 = kt * 32;
#pragma unroll
      for (int s = 0; s < 2; ++s) {
        const int m0 = wave * 32 + s * 16;
        const long long arow = (bm + m0 + r) * KH + k0 + csrc * 8;
        const long long brow = (bn + m0 + r) * KH + k0 + csrc * 8;
        GLDS(hHi + arow, &smem[0 * 4096 + m0 * 32]);
        GLDS(hLo + arow, &smem[1 * 4096 + m0 * 32]);
        GLDS(WhhHi + brow, &smem[2 * 4096 + m0 * 32]);
        GLDS(WhhLo + brow, &smem[3 * 4096 + m0 * 32]);
      }
      __syncthreads();
      bf16x8 bh[4], bl[4];
#pragma unroll
      for (int jj = 0; jj < 4; ++jj) {
        const int n = wn + jj * 16 + m15;
        bh[jj] = *(const bf16x8*)&smem[2 * 4096 + n * 32 + slot * 8];
        bl[jj] = *(const bf16x8*)&smem[3 * 4096 + n * 32 + slot * 8];
      }
#pragma unroll
      for (int i = 0; i < 4; ++i) {
        const int m = wm + i * 16 + m15;
        bf16x8 ah = *(const bf16x8*)&smem[0 * 4096 + m * 32 + slot * 8];
        bf16x8 al = *(const bf16x8*)&smem[1 * 4096 + m * 32 + slot * 8];
#pragma unroll
        for (int jj = 0; jj < 4; ++jj) {
          acc[i][jj] = __builtin_amdgcn_mfma_f32_16x16x32_bf16(ah, bh[jj], acc[i][jj], 0, 0, 0);
          acc[i][jj] = __builtin_amdgcn_mfma_f32_16x16x32_bf16(ah, bl[jj], acc[i][jj], 0, 0, 0);
          acc[i][jj] = __builtin_amdgcn_mfma_f32_16x16x32_bf16(al, bh[jj], acc[i][jj], 0, 0, 0);
        }
      }
      __syncthreads();
    }
    const int rq = (lane >> 4) * 4;
#pragma unroll
    for (int i = 0; i < 4; ++i)
#pragma unroll
      for (int j = 0; j < 4; ++j) {
        const long long n = bn + wn + j * 16 + m15;
#pragma unroll
        for (int rg = 0; rg < 4; ++rg) {
          const long long m = bm + wm + i * 16 + rq + rg;
          Gh[m * (3 * KH) + n] = acc[i][j][rg];
        }
      }
  } else {
    // ---- head path (1-product, bf16 epilogue v = logit + head_b) ----
    const int k = bid - gh_nb;
    const long long bm = (long long)(k >> 5) * 128;
    const long long bn = (long long)(k & 31) * 128;
    for (int kt = 0; kt < 24; ++kt) {
      const int k0 = kt * 32;
#pragma unroll
      for (int s = 0; s < 2; ++s) {
        const int m0 = wave * 32 + s * 16;
        const long long arow = (bm + m0 + r) * KH + k0 + csrc * 8;
        const long long brow = (bn + m0 + r) * KH + k0 + csrc * 8;
        GLDS(hHi + arow, &smem[0 * 4096 + m0 * 32]);
        GLDS(HwHi + brow, &smem[1 * 4096 + m0 * 32]);
      }
      __syncthreads();
      bf16x8 bh[4];
#pragma unroll
      for (int jj = 0; jj < 4; ++jj) {
        const int n = wn + jj * 16 + m15;
        bh[jj] = *(const bf16x8*)&smem[1 * 4096 + n * 32 + slot * 8];
      }
#pragma unroll
      for (int i = 0; i < 4; ++i) {
        const int m = wm + i * 16 + m15;
        bf16x8 ah = *(const bf16x8*)&smem[0 * 4096 + m * 32 + slot * 8];
#pragma unroll
        for (int jj = 0; jj < 4; ++jj)
          acc[i][jj] = __builtin_amdgcn_mfma_f32_16x16x32_bf16(ah, bh[jj], acc[i][jj], 0, 0, 0);
      }
      __syncthreads();
    }
    const int rq = (lane >> 4) * 4;
#pragma unroll
    for (int i = 0; i < 4; ++i)
#pragma unroll
      for (int j = 0; j < 4; ++j) {
        const long long n = bn + wn + j * 16 + m15;
        const float hb = head_b[n];
#pragma unroll
        for (int rg = 0; rg < 4; ++rg) {
          const long long m = bm + wm + i * 16 + rq + rg;
          Vbuf[m * KA + n] = f2bf(acc[i][j][rg] + hb);
        }
      }
  }
}

// ---------------------------------------------------------------------------
// Merged preamble: bf16 hi/lo splits + empty[] rows of x_.
// ---------------------------------------------------------------------------
#define CUM1 442368   // w_ih  (3*768*768/4)
#define CUM2 884736   // w_hh
#define CUM3 1671168  // head_w (+4096*768/4)
#define CUM4 2457600  // cls
#define CUM5 3244032  // ae_w
#define PREP_CONV_BLOCKS 12672  // CUM5/256

__global__ void prep(const float* __restrict__ w_ih, const float* __restrict__ w_hh,
                     const float* __restrict__ head_w, const float* __restrict__ cls,
                     const float* __restrict__ ae_w, const float* __restrict__ x_,
                     ushort* __restrict__ WihHi, ushort* __restrict__ WihLo,
                     ushort* __restrict__ WhhHi, ushort* __restrict__ WhhLo,
                     ushort* __restrict__ HwHi, ushort* __restrict__ CAhi,
                     ushort* __restrict__ CAlo, unsigned char* __restrict__ empty) {
  const int blk = blockIdx.x;
  const int tid = threadIdx.x;
  if (blk < PREP_CONV_BLOCKS) {
    const int i = blk * 256 + tid;
    const float* src; ushort* dhi; ushort* dlo; int base; int split; int ofs = 0;
    if (i < CUM1)      { src = w_ih;   dhi = WihHi; dlo = WihLo; base = 0;    split = 1; }
    else if (i < CUM2) { src = w_hh;   dhi = WhhHi; dlo = WhhLo; base = CUM1; split = 1; }
    else if (i < CUM3) { src = head_w; dhi = HwHi;  dlo = 0;     base = CUM2; split = 0; }
    else if (i < CUM4) { src = cls;    dhi = CAhi;  dlo = CAlo;  base = CUM3; split = 1; }
    else               { src = ae_w;   dhi = CAhi;  dlo = CAlo;  base = CUM4; split = 1; ofs = 786432; }
    const int k = i - base;
    float4 v = ((const float4*)src)[k];
    ushort4 h;
    h.x = f2bf(v.x); h.y = f2bf(v.y); h.z = f2bf(v.z); h.w = f2bf(v.w);
    ((ushort4*)dhi)[ofs + k] = h;
    if (split) {
      ushort4 l;
      l.x = f2bf(v.x - bf2f(h.x)); l.y = f2bf(v.y - bf2f(h.y));
      l.z = f2bf(v.z - bf2f(h.z)); l.w = f2bf(v.w - bf2f(h.w));
      ((ushort4*)dlo)[ofs + k] = l;
    }
  } else {
    const int row = blk - PREP_CONV_BLOCKS;  // 0..4095
    __shared__ int scnt[256];
    const float4* xr = (const float4*)(x_ + (size_t)row * KA);
    int cnt = 0;
#pragma unroll
    for (int k = 0; k < 4; ++k) {
      float4 v = xr[tid + (k << 8)];
      cnt += (v.x != 0.f) + (v.y != 0.f) + (v.z != 0.f) + (v.w != 0.f);
    }
    scnt[tid] = cnt;
    __syncthreads();
    for (int s = 128; s > 0; s >>= 1) {
      if (tid < s) scnt[tid] += scnt[tid + s];
      __syncthreads();
    }
    if (tid == 0) empty[row] = (scnt[0] == 0) ? 1 : 0;
  }
}

// GRU gates (f32x4 vectorized): gi = P[b] (+ AE[idx_prev[b]]) + b_ih;
// gh from Gh GEMM (j>0). h fp32 + bf16 hi/lo planes written.
__global__ void gru_gate2(const float* __restrict__ PAE, const float* __restrict__ Gh,
                          const int* __restrict__ idxbuf,
                          const float* __restrict__ b_ih, const float* __restrict__ b_hh,
                          float* __restrict__ h, ushort* __restrict__ hHi,
                          ushort* __restrict__ hLo, int first) {
  int i4 = blockIdx.x * 256 + threadIdx.x;  // over B*KH/4
  int b = i4 / (KH / 4);
  int c4 = i4 - b * (KH / 4);
  const f32x4* gp = (const f32x4*)(PAE + (size_t)b * (3 * KH));
  f32x4 ir = gp[c4], iz = gp[c4 + 192], inn = gp[c4 + 384];
  const f32x4* bi = (const f32x4*)b_ih;
  const f32x4* bhh = (const f32x4*)b_hh;
  f32x4 hr = bhh[c4], hz = bhh[c4 + 192], hn = bhh[c4 + 384];
  f32x4 hp = (f32x4){0.f, 0.f, 0.f, 0.f};
  if (!first) {
    const f32x4* ga = (const f32x4*)(PAE + ((size_t)KB + idxbuf[b]) * (3 * KH));
    ir += ga[c4]; iz += ga[c4 + 192]; inn += ga[c4 + 384];
    const f32x4* gh = (const f32x4*)(Gh + (size_t)b * (3 * KH));
    hr += gh[c4]; hz += gh[c4 + 192]; hn += gh[c4 + 384];
    hp = ((const f32x4*)h)[i4];
  }
  ir += bi[c4]; iz += bi[c4 + 192]; inn += bi[c4 + 384];
  f32x4 hv;
  ushort4 hh, hl;
  ushort* hhp = &hh.x;
  ushort* hlp = &hl.x;
#pragma unroll
  for (int e = 0; e < 4; ++e) {
    float rr = 1.f / (1.f + expf(-(ir[e] + hr[e])));
    float z = 1.f / (1.f + expf(-(iz[e] + hz[e])));
    float n = tanhf(inn[e] + rr * hn[e]);
    float v = (1.f - z) * n + z * hp[e];
    hv[e] = v;
    ushort hb = f2bf(v);
    hhp[e] = hb;
    hlp[e] = f2bf(v - bf2f(hb));
  }
  ((f32x4*)h)[i4] = hv;
  ((ushort4*)hHi)[i4] = hh;
  ((ushort4*)hLo)[i4] = hl;
}

// One block per batch row: approx vals from bf16 Vbuf, single max-reduction,
// eps-window collect, exact fp32 refinement, one-hot + mask write.
__global__ __launch_bounds__(256) void sample_step(
    float* __restrict__ out, const ushort* __restrict__ Vbuf,
    const float* __restrict__ x_, unsigned char* __restrict__ mask,
    int* __restrict__ idxbuf, const float* __restrict__ hbuf,
    const float* __restrict__ head_w, const float* __restrict__ head_b,
    const unsigned char* __restrict__ empty, int j, unsigned s0, unsigned s1) {
  const int b = blockIdx.x;
  const int tid = threadIdx.x;
  float* orow = out + ((size_t)b * KL + j) * KA;
  unsigned char* mrow = mask + (size_t)b * KA;
  const ushort* vrow = Vbuf + (size_t)b * KA;
  const float4* xrow4 = (const float4*)(x_ + (size_t)b * KA);
  __shared__ float sv[256];
  __shared__ int scand[16];
  __shared__ float srefined[16];
  __shared__ int scnt;
  __shared__ int ssel;
  const float EPS = 0.02f;  // covers bf16 logit err (~4e-3) + bf16 store (~3e-3), x2

  if (tid == 0) scnt = 0;

  const int idx_prev = (j > 0) ? idxbuf[b] : 0;
  const int emp = (j == 0) ? empty[b] : 0;

  // Phase 1: approx candidate values into registers (8 atoms per chunk).
  float vreg[16];
  unsigned mbits = 0;
  float lmax = -INFINITY;
#pragma unroll
  for (int k = 0; k < 2; ++k) {
    const int ci = tid + (k << 8);   // uint4 index (512 per row)
    const int abase = ci * 8;
    uint4 vv = ((const uint4*)vrow)[ci];
    unsigned vw[4] = {vv.x, vv.y, vv.z, vv.w};
    float xv[8];
    unsigned mw0 = 0, mw1 = 0;
    if (j == 0) {
      float4 x0 = xrow4[ci * 2], x1 = xrow4[ci * 2 + 1];
      xv[0] = x0.x; xv[1] = x0.y; xv[2] = x0.z; xv[3] = x0.w;
      xv[4] = x1.x; xv[5] = x1.y; xv[6] = x1.z; xv[7] = x1.w;
    } else {
      uint2 mwv = ((const uint2*)mrow)[ci];
      mw0 = mwv.x; mw1 = mwv.y;
    }
#pragma unroll
    for (int e = 0; e < 8; ++e) {
      const int a = abase + e;
      int m;
      if (j == 0) {
        m = (xv[e] != 0.f) || (emp && a == 0);
      } else {
        unsigned mb = (e < 4) ? ((mw0 >> (8 * e)) & 0xffu)
                              : ((mw1 >> (8 * (e - 4))) & 0xffu);
        m = (a == 0) || (idx_prev != 0 && mb);
      }
      float v = -INFINITY;
      if (m) {
        ushort hv16 = (ushort)((vw[e >> 1] >> (16 * (e & 1))) & 0xffffu);
        float g = gumbel_at(s0, s1, (unsigned)(b * KA + a));
        v = bf2f(hv16) + g;
        mbits |= (1u << (k * 8 + e));
      }
      vreg[k * 8 + e] = v;
      lmax = fmaxf(lmax, v);
    }
  }
  // Phase 2: single block max-reduction.
  sv[tid] = lmax;
  __syncthreads();
  for (int s = 128; s > 0; s >>= 1) {
    if (tid < s) sv[tid] = fmaxf(sv[tid], sv[tid + s]);
    __syncthreads();
  }
  const float vmax = sv[0];

  // Phase 3: collect eps-window candidates (<=16; typically 1).
  const float thresh = vmax - EPS;
#pragma unroll
  for (int k = 0; k < 2; ++k)
#pragma unroll
    for (int e = 0; e < 8; ++e) {
      if (vreg[k * 8 + e] >= thresh) {
        int slot = atomicAdd(&scnt, 1);
        if (slot < 16) scand[slot] = (tid + (k << 8)) * 8 + e;
      }
    }
  __syncthreads();
  const int ncand = min(scnt, 16);

  // Phase 4: exact fp32 refinement; wave w handles candidates w, w+4, ...
  {
    const int wv = tid >> 6;
    const int lane = tid & 63;
    const float4* h4 = (const float4*)(hbuf + (size_t)b * KH);
    for (int t = wv; t < ncand; t += 4) {
      const int a = scand[t];
      const float4* w4 = (const float4*)(head_w + (size_t)a * KH);
      float sum = 0.f;
#pragma unroll
      for (int u = 0; u < 3; ++u) {
        float4 hv = h4[lane + u * 64];
        float4 wv4 = w4[lane + u * 64];
        sum = fmaf(hv.x, wv4.x, sum);
        sum = fmaf(hv.y, wv4.y, sum);
        sum = fmaf(hv.z, wv4.z, sum);
        sum = fmaf(hv.w, wv4.w, sum);
      }
#pragma unroll
      for (int off = 32; off > 0; off >>= 1) sum += __shfl_down(sum, off);
      if (lane == 0) {
        float g = gumbel_at(s0, s1, (unsigned)(b * KA + a));
        srefined[t] = sum + head_b[a] + g;
      }
    }
  }
  __syncthreads();

  // Phase 5: final argmax over refined candidates (lower index on ties).
  if (tid == 0) {
    float best = -INFINITY;
    int bsel = KA;
    for (int t = 0; t < ncand; ++t) {
      float v = srefined[t];
      int a = scand[t];
      if (v > best || (v == best && a < bsel)) { best = v; bsel = a; }
    }
    ssel = bsel;
  }
  __syncthreads();
  const int sel = ssel;

  // Phase 6: one-hot + mask update (vectorized stores, 8 atoms per chunk).
#pragma unroll
  for (int k = 0; k < 2; ++k) {
    const int ci = tid + (k << 8);
    const int abase = ci * 8;
    unsigned mw[2] = {0u, 0u};
    float ov[8];
#pragma unroll
    for (int e = 0; e < 8; ++e) {
      const int a = abase + e;
      int m = (mbits >> (k * 8 + e)) & 1;
      if (a == sel) m = 0;
      mw[e >> 2] |= ((unsigned)m) << (8 * (e & 3));
      ov[e] = (a == sel) ? 1.f : 0.f;
    }
    ((uint2*)mrow)[ci] = make_uint2(mw[0], mw[1]);
    ((float4*)orow)[ci * 2]     = make_float4(ov[0], ov[1], ov[2], ov[3]);
    ((float4*)orow)[ci * 2 + 1] = make_float4(ov[4], ov[5], ov[6], ov[7]);
  }
  if (tid == 0) idxbuf[b] = sel;
}

extern "C" void kernel_launch(void* const* d_in, const int* in_sizes, int n_in,
                              void* d_out, int out_size, void* d_ws, size_t ws_size,
                              hipStream_t stream) {
  const float* cls    = (const float*)d_in[0];
  const float* x_     = (const float*)d_in[1];
  const float* w_ih   = (const float*)d_in[2];
  const float* w_hh   = (const float*)d_in[3];
  const float* b_ih   = (const float*)d_in[4];
  const float* b_hh   = (const float*)d_in[5];
  const float* head_w = (const float*)d_in[6];
  const float* head_b = (const float*)d_in[7];
  const float* ae_w   = (const float*)d_in[8];
  float* out = (float*)d_out;

  char* p = (char*)d_ws;
  ushort* CAhi  = (ushort*)p; p += (size_t)2 * KB * KH * 2;     // [cls; ae_w] hi
  ushort* CAlo  = (ushort*)p; p += (size_t)2 * KB * KH * 2;
  ushort* WihHi = (ushort*)p; p += (size_t)3 * KH * KH * 2;
  ushort* WihLo = (ushort*)p; p += (size_t)3 * KH * KH * 2;
  ushort* WhhHi = (ushort*)p; p += (size_t)3 * KH * KH * 2;
  ushort* WhhLo = (ushort*)p; p += (size_t)3 * KH * KH * 2;
  ushort* HwHi  = (ushort*)p; p += (size_t)KA * KH * 2;
  ushort* hHi   = (ushort*)p; p += (size_t)KB * KH * 2;
  ushort* hLo   = (ushort*)p; p += (size_t)KB * KH * 2;
  float*  hbuf  = (float*)p;  p += (size_t)KB * KH * 4;
  float*  PAE   = (float*)p;  p += (size_t)2 * KB * 3 * KH * 4; // P | AE
  float*  Gh    = (float*)p;  p += (size_t)KB * 3 * KH * 4;
  ushort* Vbuf  = (ushort*)p; p += (size_t)KB * KA * 2;         // bf16 v
  unsigned char* mask  = (unsigned char*)p; p += (size_t)KB * KA;
  unsigned char* empty = (unsigned char*)p; p += (size_t)KB;
  int* idxbuf = (int*)p; p += (size_t)KB * 4;

  // Host-side JAX key schedule (partitionable split of key(42)).
  unsigned key0 = 0u, key1 = 42u;
  unsigned sub0[KL], sub1[KL];
  for (int j = 0; j < KL; ++j) {
    unsigned n0, n1, t0, t1;
    tf2x32(key0, key1, 0u, 0u, n0, n1);
    tf2x32(key0, key1, 0u, 1u, t0, t1);
    sub0[j] = t0; sub1[j] = t1;
    key0 = n0; key1 = n1;
  }

  // Preamble: all bf16 splits + empty[] in one launch.
  prep<<<PREP_CONV_BLOCKS + KB, 256, 0, stream>>>(
      w_ih, w_hh, head_w, cls, ae_w, x_,
      WihHi, WihLo, WhhHi, WhhLo, HwHi, CAhi, CAlo, empty);
  // P = cls @ w_ih^T ; AE = ae_w @ w_ih^T  (one concatenated dispatch).
  gemm3_nt<<<dim3(3 * KH / 128, 2 * KB / 128), 256, 0, stream>>>(
      CAhi, CAlo, WihHi, WihLo, PAE, 3 * KH);

  for (int j = 0; j < KL; ++j) {
    gru_gate2<<<KB * KH / 4 / 256, 256, 0, stream>>>(PAE, Gh, idxbuf, b_ih, b_hh,
                                                     hbuf, hHi, hLo, j == 0);
    const int gh_nb = (j < KL - 1) ? 576 : 0;  // Gh_{j+1} needs only h_j
    gemm_fused<<<gh_nb + 1024, 256, 0, stream>>>(
        hHi, hLo, WhhHi, WhhLo, Gh, HwHi, head_b, Vbuf, gh_nb);
    sample_step<<<KB, 256, 0, stream>>>(out, Vbuf, x_, mask, idxbuf, hbuf,
                                        head_w, head_b, empty, j, sub0[j], sub1[j]);
  }
}

// Round 9
// 950.754 us; speedup vs baseline: 1.4675x; 1.0823x over previous
//
#include <hip/hip_runtime.h>
#include <cstdint>
#include <cstddef>
#include <math.h>

// AtomSelector: B=4096, A=4096, H=768, L=4.
// R9 = R8 + (1) sample_step_j fused with gru_gate_{j+1} (block b produces
// idx[b] then updates h[b] itself); (2) __launch_bounds__(256,4) on GEMMs
// (cap 128 VGPR -> 4 blocks/CU at 32 KB LDS).
// PRNG: JAX threefry2x32 partitionable scheme (verified exact since R0).

#define KB 4096
#define KA 4096
#define KH 768
#define KL 4

typedef __attribute__((ext_vector_type(8))) short bf16x8;
typedef __attribute__((ext_vector_type(4))) float f32x4;

__host__ __device__ inline unsigned rotl32(unsigned x, int d) {
  return (x << d) | (x >> (32 - d));
}

// Threefry-2x32, 20 rounds
__host__ __device__ inline void tf2x32(unsigned k0, unsigned k1,
                                       unsigned x0, unsigned x1,
                                       unsigned& o0, unsigned& o1) {
  unsigned ks2 = k0 ^ k1 ^ 0x1BD11BDAu;
  x0 += k0; x1 += k1;
#define TF_R(r) { x0 += x1; x1 = rotl32(x1, (r)); x1 ^= x0; }
  TF_R(13) TF_R(15) TF_R(26) TF_R(6)
  x0 += k1;  x1 += ks2 + 1u;
  TF_R(17) TF_R(29) TF_R(16) TF_R(24)
  x0 += ks2; x1 += k0 + 2u;
  TF_R(13) TF_R(15) TF_R(26) TF_R(6)
  x0 += k0;  x1 += k1 + 3u;
  TF_R(17) TF_R(29) TF_R(16) TF_R(24)
  x0 += k1;  x1 += ks2 + 4u;
  TF_R(13) TF_R(15) TF_R(26) TF_R(6)
  x0 += ks2; x1 += k0 + 5u;
#undef TF_R
  o0 = x0; o1 = x1;
}

__device__ inline ushort f2bf(float f) {
  unsigned u = __float_as_uint(f);
  unsigned r = (u + 0x7fffu + ((u >> 16) & 1u)) >> 16;
  return (ushort)r;
}
__device__ inline float bf2f(ushort h) {
  return __uint_as_float(((unsigned)h) << 16);
}

__device__ inline float gumbel_at(unsigned s0, unsigned s1, unsigned ctr) {
  unsigned o0, o1;
  tf2x32(s0, s1, 0u, ctr, o0, o1);
  unsigned bits = o0 ^ o1;
  float f = __uint_as_float((bits >> 9) | 0x3f800000u) - 1.0f;
  const float TINY = 1.17549435e-38f;
  float u = fmaxf(TINY, f + TINY);
  return -logf(-logf(u));
}

#define GLDS(gp, lp) \
  __builtin_amdgcn_global_load_lds( \
      (const __attribute__((address_space(1))) void*)(gp), \
      (__attribute__((address_space(3))) void*)(lp), 16, 0, 0)

// ---------------------------------------------------------------------------
// gemm3_nt: C[M,N] = A[M,768] @ W[N,768]^T, bf16x2 split, 3 MFMA products.
// BK=32 -> 32 KB LDS; launch_bounds(256,4) -> <=128 VGPR -> 4 blocks/CU.
// Used once for PAE = [cls; ae_w] @ w_ih^T.
// ---------------------------------------------------------------------------
__global__ __launch_bounds__(256, 4) void gemm3_nt(
    const ushort* __restrict__ Ahi, const ushort* __restrict__ Alo,
    const ushort* __restrict__ Bhi, const ushort* __restrict__ Blo,
    float* __restrict__ C, long long ldc) {
  __shared__ ushort smem[4 * 128 * 32];  // 32 KB
  const int tid = threadIdx.x;
  const int wave = tid >> 6;
  const int lane = tid & 63;
  const long long bm = (long long)blockIdx.y * 128;
  const long long bn = (long long)blockIdx.x * 128;
  const int wm = (wave & 1) * 64;
  const int wn = (wave >> 1) * 64;

  f32x4 acc[4][4];
#pragma unroll
  for (int i = 0; i < 4; ++i)
#pragma unroll
    for (int j = 0; j < 4; ++j) acc[i][j] = (f32x4){0.f, 0.f, 0.f, 0.f};

  const int r = lane >> 2;
  const int cs = lane & 3;
  const int csrc = cs ^ ((r & 3) ^ ((r >> 2) & 3));
  const int m15 = lane & 15;
  const int kg = (lane >> 4) & 3;
  const int slot = kg ^ ((m15 & 3) ^ ((m15 >> 2) & 3));

  for (int kt = 0; kt < 24; ++kt) {
    const int k0 = kt * 32;
#pragma unroll
    for (int s = 0; s < 2; ++s) {
      const int m0 = wave * 32 + s * 16;
      const long long arow = (bm + m0 + r) * KH + k0 + csrc * 8;
      const long long brow = (bn + m0 + r) * KH + k0 + csrc * 8;
      GLDS(Ahi + arow, &smem[0 * 4096 + m0 * 32]);
      GLDS(Alo + arow, &smem[1 * 4096 + m0 * 32]);
      GLDS(Bhi + brow, &smem[2 * 4096 + m0 * 32]);
      GLDS(Blo + brow, &smem[3 * 4096 + m0 * 32]);
    }
    __syncthreads();
    bf16x8 bh[4], bl[4];
#pragma unroll
    for (int jj = 0; jj < 4; ++jj) {
      const int n = wn + jj * 16 + m15;
      bh[jj] = *(const bf16x8*)&smem[2 * 4096 + n * 32 + slot * 8];
      bl[jj] = *(const bf16x8*)&smem[3 * 4096 + n * 32 + slot * 8];
    }
#pragma unroll
    for (int i = 0; i < 4; ++i) {
      const int m = wm + i * 16 + m15;
      bf16x8 ah = *(const bf16x8*)&smem[0 * 4096 + m * 32 + slot * 8];
      bf16x8 al = *(const bf16x8*)&smem[1 * 4096 + m * 32 + slot * 8];
#pragma unroll
      for (int jj = 0; jj < 4; ++jj) {
        acc[i][jj] = __builtin_amdgcn_mfma_f32_16x16x32_bf16(ah, bh[jj], acc[i][jj], 0, 0, 0);
        acc[i][jj] = __builtin_amdgcn_mfma_f32_16x16x32_bf16(ah, bl[jj], acc[i][jj], 0, 0, 0);
        acc[i][jj] = __builtin_amdgcn_mfma_f32_16x16x32_bf16(al, bh[jj], acc[i][jj], 0, 0, 0);
      }
    }
    __syncthreads();
  }
  const int rq = (lane >> 4) * 4;
#pragma unroll
  for (int i = 0; i < 4; ++i)
#pragma unroll
    for (int j = 0; j < 4; ++j) {
      const long long n = bn + wn + j * 16 + m15;
#pragma unroll
      for (int rg = 0; rg < 4; ++rg) {
        const long long m = bm + wm + i * 16 + rq + rg;
        C[m * ldc + n] = acc[i][j][rg];
      }
    }
}

// ---------------------------------------------------------------------------
// Fused per-step GEMM dispatch:
//   blocks [0, gh_nb)        : Gh_{j+1} = h_j @ w_hh^T   (bf16x2, 3 products)
//   blocks [gh_nb, gh_nb+1024): Vbuf = bf16(h_j @ head_w^T + head_b) (1 prod)
// ---------------------------------------------------------------------------
__global__ __launch_bounds__(256, 4) void gemm_fused(
    const ushort* __restrict__ hHi, const ushort* __restrict__ hLo,
    const ushort* __restrict__ WhhHi, const ushort* __restrict__ WhhLo,
    float* __restrict__ Gh, const ushort* __restrict__ HwHi,
    const float* __restrict__ head_b, ushort* __restrict__ Vbuf, int gh_nb) {
  __shared__ ushort smem[4 * 128 * 32];  // 32 KB (head path uses 2 planes)
  const int tid = threadIdx.x;
  const int wave = tid >> 6;
  const int lane = tid & 63;
  const int bid = blockIdx.x;
  const int wm = (wave & 1) * 64;
  const int wn = (wave >> 1) * 64;
  const int r = lane >> 2;
  const int cs = lane & 3;
  const int csrc = cs ^ ((r & 3) ^ ((r >> 2) & 3));
  const int m15 = lane & 15;
  const int kg = (lane >> 4) & 3;
  const int slot = kg ^ ((m15 & 3) ^ ((m15 >> 2) & 3));

  f32x4 acc[4][4];
#pragma unroll
  for (int i = 0; i < 4; ++i)
#pragma unroll
    for (int j = 0; j < 4; ++j) acc[i][j] = (f32x4){0.f, 0.f, 0.f, 0.f};

  if (bid < gh_nb) {
    // ---- gh path (3-product) ----
    const long long bm = (long long)(bid / 18) * 128;
    const long long bn = (long long)(bid % 18) * 128;
    for (int kt = 0; kt < 24; ++kt) {
      const int k0 = kt * 32;
#pragma unroll
      for (int s = 0; s < 2; ++s) {
        const int m0 = wave * 32 + s * 16;
        const long long arow = (bm + m0 + r) * KH + k0 + csrc * 8;
        const long long brow = (bn + m0 + r) * KH + k0 + csrc * 8;
        GLDS(hHi + arow, &smem[0 * 4096 + m0 * 32]);
        GLDS(hLo + arow, &smem[1 * 4096 + m0 * 32]);
        GLDS(WhhHi + brow, &smem[2 * 4096 + m0 * 32]);
        GLDS(WhhLo + brow, &smem[3 * 4096 + m0 * 32]);
      }
      __syncthreads();
      bf16x8 bh[4], bl[4];
#pragma unroll
      for (int jj = 0; jj < 4; ++jj) {
        const int n = wn + jj * 16 + m15;
        bh[jj] = *(const bf16x8*)&smem[2 * 4096 + n * 32 + slot * 8];
        bl[jj] = *(const bf16x8*)&smem[3 * 4096 + n * 32 + slot * 8];
      }
#pragma unroll
      for (int i = 0; i < 4; ++i) {
        const int m = wm + i * 16 + m15;
        bf16x8 ah = *(const bf16x8*)&smem[0 * 4096 + m * 32 + slot * 8];
        bf16x8 al = *(const bf16x8*)&smem[1 * 4096 + m * 32 + slot * 8];
#pragma unroll
        for (int jj = 0; jj < 4; ++jj) {
          acc[i][jj] = __builtin_amdgcn_mfma_f32_16x16x32_bf16(ah, bh[jj], acc[i][jj], 0, 0, 0);
          acc[i][jj] = __builtin_amdgcn_mfma_f32_16x16x32_bf16(ah, bl[jj], acc[i][jj], 0, 0, 0);
          acc[i][jj] = __builtin_amdgcn_mfma_f32_16x16x32_bf16(al, bh[jj], acc[i][jj], 0, 0, 0);
        }
      }
      __syncthreads();
    }
    const int rq = (lane >> 4) * 4;
#pragma unroll
    for (int i = 0; i < 4; ++i)
#pragma unroll
      for (int j = 0; j < 4; ++j) {
        const long long n = bn + wn + j * 16 + m15;
#pragma unroll
        for (int rg = 0; rg < 4; ++rg) {
          const long long m = bm + wm + i * 16 + rq + rg;
          Gh[m * (3 * KH) + n] = acc[i][j][rg];
        }
      }
  } else {
    // ---- head path (1-product, bf16 epilogue v = logit + head_b) ----
    const int k = bid - gh_nb;
    const long long bm = (long long)(k >> 5) * 128;
    const long long bn = (long long)(k & 31) * 128;
    for (int kt = 0; kt < 24; ++kt) {
      const int k0 = kt * 32;
#pragma unroll
      for (int s = 0; s < 2; ++s) {
        const int m0 = wave * 32 + s * 16;
        const long long arow = (bm + m0 + r) * KH + k0 + csrc * 8;
        const long long brow = (bn + m0 + r) * KH + k0 + csrc * 8;
        GLDS(hHi + arow, &smem[0 * 4096 + m0 * 32]);
        GLDS(HwHi + brow, &smem[1 * 4096 + m0 * 32]);
      }
      __syncthreads();
      bf16x8 bh[4];
#pragma unroll
      for (int jj = 0; jj < 4; ++jj) {
        const int n = wn + jj * 16 + m15;
        bh[jj] = *(const bf16x8*)&smem[1 * 4096 + n * 32 + slot * 8];
      }
#pragma unroll
      for (int i = 0; i < 4; ++i) {
        const int m = wm + i * 16 + m15;
        bf16x8 ah = *(const bf16x8*)&smem[0 * 4096 + m * 32 + slot * 8];
#pragma unroll
        for (int jj = 0; jj < 4; ++jj)
          acc[i][jj] = __builtin_amdgcn_mfma_f32_16x16x32_bf16(ah, bh[jj], acc[i][jj], 0, 0, 0);
      }
      __syncthreads();
    }
    const int rq = (lane >> 4) * 4;
#pragma unroll
    for (int i = 0; i < 4; ++i)
#pragma unroll
      for (int j = 0; j < 4; ++j) {
        const long long n = bn + wn + j * 16 + m15;
        const float hb = head_b[n];
#pragma unroll
        for (int rg = 0; rg < 4; ++rg) {
          const long long m = bm + wm + i * 16 + rq + rg;
          Vbuf[m * KA + n] = f2bf(acc[i][j][rg] + hb);
        }
      }
  }
}

// ---------------------------------------------------------------------------
// Merged preamble: bf16 hi/lo splits + empty[] rows of x_.
// ---------------------------------------------------------------------------
#define CUM1 442368   // w_ih  (3*768*768/4)
#define CUM2 884736   // w_hh
#define CUM3 1671168  // head_w (+4096*768/4)
#define CUM4 2457600  // cls
#define CUM5 3244032  // ae_w
#define PREP_CONV_BLOCKS 12672  // CUM5/256

__global__ void prep(const float* __restrict__ w_ih, const float* __restrict__ w_hh,
                     const float* __restrict__ head_w, const float* __restrict__ cls,
                     const float* __restrict__ ae_w, const float* __restrict__ x_,
                     ushort* __restrict__ WihHi, ushort* __restrict__ WihLo,
                     ushort* __restrict__ WhhHi, ushort* __restrict__ WhhLo,
                     ushort* __restrict__ HwHi, ushort* __restrict__ CAhi,
                     ushort* __restrict__ CAlo, unsigned char* __restrict__ empty) {
  const int blk = blockIdx.x;
  const int tid = threadIdx.x;
  if (blk < PREP_CONV_BLOCKS) {
    const int i = blk * 256 + tid;
    const float* src; ushort* dhi; ushort* dlo; int base; int split; int ofs = 0;
    if (i < CUM1)      { src = w_ih;   dhi = WihHi; dlo = WihLo; base = 0;    split = 1; }
    else if (i < CUM2) { src = w_hh;   dhi = WhhHi; dlo = WhhLo; base = CUM1; split = 1; }
    else if (i < CUM3) { src = head_w; dhi = HwHi;  dlo = 0;     base = CUM2; split = 0; }
    else if (i < CUM4) { src = cls;    dhi = CAhi;  dlo = CAlo;  base = CUM3; split = 1; }
    else               { src = ae_w;   dhi = CAhi;  dlo = CAlo;  base = CUM4; split = 1; ofs = 786432; }
    const int k = i - base;
    float4 v = ((const float4*)src)[k];
    ushort4 h;
    h.x = f2bf(v.x); h.y = f2bf(v.y); h.z = f2bf(v.z); h.w = f2bf(v.w);
    ((ushort4*)dhi)[ofs + k] = h;
    if (split) {
      ushort4 l;
      l.x = f2bf(v.x - bf2f(h.x)); l.y = f2bf(v.y - bf2f(h.y));
      l.z = f2bf(v.z - bf2f(h.z)); l.w = f2bf(v.w - bf2f(h.w));
      ((ushort4*)dlo)[ofs + k] = l;
    }
  } else {
    const int row = blk - PREP_CONV_BLOCKS;  // 0..4095
    __shared__ int scnt[256];
    const float4* xr = (const float4*)(x_ + (size_t)row * KA);
    int cnt = 0;
#pragma unroll
    for (int k = 0; k < 4; ++k) {
      float4 v = xr[tid + (k << 8)];
      cnt += (v.x != 0.f) + (v.y != 0.f) + (v.z != 0.f) + (v.w != 0.f);
    }
    scnt[tid] = cnt;
    __syncthreads();
    for (int s = 128; s > 0; s >>= 1) {
      if (tid < s) scnt[tid] += scnt[tid + s];
      __syncthreads();
    }
    if (tid == 0) empty[row] = (scnt[0] == 0) ? 1 : 0;
  }
}

// GRU gate for j=0 only (first=1 path: gi = P[b] + b_ih, gh = b_hh, h_prev=0).
__global__ void gru_gate0(const float* __restrict__ PAE,
                          const float* __restrict__ b_ih, const float* __restrict__ b_hh,
                          float* __restrict__ h, ushort* __restrict__ hHi,
                          ushort* __restrict__ hLo) {
  int i4 = blockIdx.x * 256 + threadIdx.x;  // over B*KH/4
  int b = i4 / (KH / 4);
  int c4 = i4 - b * (KH / 4);
  const f32x4* gp = (const f32x4*)(PAE + (size_t)b * (3 * KH));
  const f32x4* bi = (const f32x4*)b_ih;
  const f32x4* bhh = (const f32x4*)b_hh;
  f32x4 ir = gp[c4] + bi[c4];
  f32x4 iz = gp[c4 + 192] + bi[c4 + 192];
  f32x4 inn = gp[c4 + 384] + bi[c4 + 384];
  f32x4 hr = bhh[c4], hz = bhh[c4 + 192], hn = bhh[c4 + 384];
  f32x4 hv;
  ushort4 hh, hl;
  ushort* hhp = &hh.x;
  ushort* hlp = &hl.x;
#pragma unroll
  for (int e = 0; e < 4; ++e) {
    float rr = 1.f / (1.f + expf(-(ir[e] + hr[e])));
    float z = 1.f / (1.f + expf(-(iz[e] + hz[e])));
    float n = tanhf(inn[e] + rr * hn[e]);
    float v = (1.f - z) * n;  // h_prev = 0
    hv[e] = v;
    ushort hb = f2bf(v);
    hhp[e] = hb;
    hlp[e] = f2bf(v - bf2f(hb));
  }
  ((f32x4*)h)[i4] = hv;
  ((ushort4*)hHi)[i4] = hh;
  ((ushort4*)hLo)[i4] = hl;
}

// One block per batch row: sample (approx vals from bf16 Vbuf, eps-window
// collect, exact fp32 refinement, one-hot + mask write) THEN, fused, the
// GRU gate for step j+1 of the same row (needs only this row's sel).
__global__ __launch_bounds__(256) void sample_gate(
    float* __restrict__ out, const ushort* __restrict__ Vbuf,
    const float* __restrict__ x_, unsigned char* __restrict__ mask,
    int* __restrict__ idxbuf, float* __restrict__ hbuf,
    const float* __restrict__ head_w, const float* __restrict__ head_b,
    const unsigned char* __restrict__ empty,
    const float* __restrict__ PAE, const float* __restrict__ Gh,
    const float* __restrict__ b_ih, const float* __restrict__ b_hh,
    ushort* __restrict__ hHi, ushort* __restrict__ hLo,
    int j, int do_gate, unsigned s0, unsigned s1) {
  const int b = blockIdx.x;
  const int tid = threadIdx.x;
  float* orow = out + ((size_t)b * KL + j) * KA;
  unsigned char* mrow = mask + (size_t)b * KA;
  const ushort* vrow = Vbuf + (size_t)b * KA;
  const float4* xrow4 = (const float4*)(x_ + (size_t)b * KA);
  __shared__ float sv[256];
  __shared__ int scand[16];
  __shared__ float srefined[16];
  __shared__ int scnt;
  __shared__ int ssel;
  const float EPS = 0.02f;  // bf16 logit err + bf16 store rounding, x2 margin

  if (tid == 0) scnt = 0;

  const int idx_prev = (j > 0) ? idxbuf[b] : 0;
  const int emp = (j == 0) ? empty[b] : 0;

  // Phase 1: approx candidate values into registers (8 atoms per chunk).
  float vreg[16];
  unsigned mbits = 0;
  float lmax = -INFINITY;
#pragma unroll
  for (int k = 0; k < 2; ++k) {
    const int ci = tid + (k << 8);   // uint4 index (512 per row)
    const int abase = ci * 8;
    uint4 vv = ((const uint4*)vrow)[ci];
    unsigned vw[4] = {vv.x, vv.y, vv.z, vv.w};
    float xv[8];
    unsigned mw0 = 0, mw1 = 0;
    if (j == 0) {
      float4 x0 = xrow4[ci * 2], x1 = xrow4[ci * 2 + 1];
      xv[0] = x0.x; xv[1] = x0.y; xv[2] = x0.z; xv[3] = x0.w;
      xv[4] = x1.x; xv[5] = x1.y; xv[6] = x1.z; xv[7] = x1.w;
    } else {
      uint2 mwv = ((const uint2*)mrow)[ci];
      mw0 = mwv.x; mw1 = mwv.y;
    }
#pragma unroll
    for (int e = 0; e < 8; ++e) {
      const int a = abase + e;
      int m;
      if (j == 0) {
        m = (xv[e] != 0.f) || (emp && a == 0);
      } else {
        unsigned mb = (e < 4) ? ((mw0 >> (8 * e)) & 0xffu)
                              : ((mw1 >> (8 * (e - 4))) & 0xffu);
        m = (a == 0) || (idx_prev != 0 && mb);
      }
      float v = -INFINITY;
      if (m) {
        ushort hv16 = (ushort)((vw[e >> 1] >> (16 * (e & 1))) & 0xffffu);
        float g = gumbel_at(s0, s1, (unsigned)(b * KA + a));
        v = bf2f(hv16) + g;
        mbits |= (1u << (k * 8 + e));
      }
      vreg[k * 8 + e] = v;
      lmax = fmaxf(lmax, v);
    }
  }
  // Phase 2: single block max-reduction.
  sv[tid] = lmax;
  __syncthreads();
  for (int s = 128; s > 0; s >>= 1) {
    if (tid < s) sv[tid] = fmaxf(sv[tid], sv[tid + s]);
    __syncthreads();
  }
  const float vmax = sv[0];

  // Phase 3: collect eps-window candidates (<=16; typically 1).
  const float thresh = vmax - EPS;
#pragma unroll
  for (int k = 0; k < 2; ++k)
#pragma unroll
    for (int e = 0; e < 8; ++e) {
      if (vreg[k * 8 + e] >= thresh) {
        int slot = atomicAdd(&scnt, 1);
        if (slot < 16) scand[slot] = (tid + (k << 8)) * 8 + e;
      }
    }
  __syncthreads();
  const int ncand = min(scnt, 16);

  // Phase 4: exact fp32 refinement; wave w handles candidates w, w+4, ...
  {
    const int wv = tid >> 6;
    const int lane = tid & 63;
    const float4* h4 = (const float4*)(hbuf + (size_t)b * KH);
    for (int t = wv; t < ncand; t += 4) {
      const int a = scand[t];
      const float4* w4 = (const float4*)(head_w + (size_t)a * KH);
      float sum = 0.f;
#pragma unroll
      for (int u = 0; u < 3; ++u) {
        float4 hv = h4[lane + u * 64];
        float4 wv4 = w4[lane + u * 64];
        sum = fmaf(hv.x, wv4.x, sum);
        sum = fmaf(hv.y, wv4.y, sum);
        sum = fmaf(hv.z, wv4.z, sum);
        sum = fmaf(hv.w, wv4.w, sum);
      }
#pragma unroll
      for (int off = 32; off > 0; off >>= 1) sum += __shfl_down(sum, off);
      if (lane == 0) {
        float g = gumbel_at(s0, s1, (unsigned)(b * KA + a));
        srefined[t] = sum + head_b[a] + g;
      }
    }
  }
  __syncthreads();

  // Phase 5: final argmax over refined candidates (lower index on ties).
  if (tid == 0) {
    float best = -INFINITY;
    int bsel = KA;
    for (int t = 0; t < ncand; ++t) {
      float v = srefined[t];
      int a = scand[t];
      if (v > best || (v == best && a < bsel)) { best = v; bsel = a; }
    }
    ssel = bsel;
  }
  __syncthreads();
  const int sel = ssel;

  // Phase 6: one-hot + mask update (vectorized stores, 8 atoms per chunk).
#pragma unroll
  for (int k = 0; k < 2; ++k) {
    const int ci = tid + (k << 8);
    const int abase = ci * 8;
    unsigned mw[2] = {0u, 0u};
    float ov[8];
#pragma unroll
    for (int e = 0; e < 8; ++e) {
      const int a = abase + e;
      int m = (mbits >> (k * 8 + e)) & 1;
      if (a == sel) m = 0;
      mw[e >> 2] |= ((unsigned)m) << (8 * (e & 3));
      ov[e] = (a == sel) ? 1.f : 0.f;
    }
    ((uint2*)mrow)[ci] = make_uint2(mw[0], mw[1]);
    ((float4*)orow)[ci * 2]     = make_float4(ov[0], ov[1], ov[2], ov[3]);
    ((float4*)orow)[ci * 2 + 1] = make_float4(ov[4], ov[5], ov[6], ov[7]);
  }
  if (tid == 0) idxbuf[b] = sel;

  // Phase 7 (fused GRU gate for step j+1, this row only): needs sel + Gh[b]
  // (written by the previous gemm_fused dispatch) + h_j[b] (this row's hbuf,
  // read after phase-4 refinement is done -> in-block ordering is safe).
  if (do_gate && tid < 192) {
    const int c4 = tid;
    const int i4 = b * (KH / 4) + c4;
    const f32x4* gp = (const f32x4*)(PAE + (size_t)b * (3 * KH));
    const f32x4* ga = (const f32x4*)(PAE + ((size_t)KB + sel) * (3 * KH));
    const f32x4* bi = (const f32x4*)b_ih;
    const f32x4* bhh = (const f32x4*)b_hh;
    const f32x4* gh4 = (const f32x4*)(Gh + (size_t)b * (3 * KH));
    f32x4 ir = gp[c4] + ga[c4] + bi[c4];
    f32x4 iz = gp[c4 + 192] + ga[c4 + 192] + bi[c4 + 192];
    f32x4 inn = gp[c4 + 384] + ga[c4 + 384] + bi[c4 + 384];
    f32x4 hr = bhh[c4] + gh4[c4];
    f32x4 hz = bhh[c4 + 192] + gh4[c4 + 192];
    f32x4 hn = bhh[c4 + 384] + gh4[c4 + 384];
    f32x4 hp = ((const f32x4*)hbuf)[i4];
    f32x4 hv;
    ushort4 hh, hl;
    ushort* hhp = &hh.x;
    ushort* hlp = &hl.x;
#pragma unroll
    for (int e = 0; e < 4; ++e) {
      float rr = 1.f / (1.f + expf(-(ir[e] + hr[e])));
      float z = 1.f / (1.f + expf(-(iz[e] + hz[e])));
      float n = tanhf(inn[e] + rr * hn[e]);
      float v = (1.f - z) * n + z * hp[e];
      hv[e] = v;
      ushort hb = f2bf(v);
      hhp[e] = hb;
      hlp[e] = f2bf(v - bf2f(hb));
    }
    ((f32x4*)hbuf)[i4] = hv;
    ((ushort4*)hHi)[i4] = hh;
    ((ushort4*)hLo)[i4] = hl;
  }
}

extern "C" void kernel_launch(void* const* d_in, const int* in_sizes, int n_in,
                              void* d_out, int out_size, void* d_ws, size_t ws_size,
                              hipStream_t stream) {
  const float* cls    = (const float*)d_in[0];
  const float* x_     = (const float*)d_in[1];
  const float* w_ih   = (const float*)d_in[2];
  const float* w_hh   = (const float*)d_in[3];
  const float* b_ih   = (const float*)d_in[4];
  const float* b_hh   = (const float*)d_in[5];
  const float* head_w = (const float*)d_in[6];
  const float* head_b = (const float*)d_in[7];
  const float* ae_w   = (const float*)d_in[8];
  float* out = (float*)d_out;

  char* p = (char*)d_ws;
  ushort* CAhi  = (ushort*)p; p += (size_t)2 * KB * KH * 2;     // [cls; ae_w] hi
  ushort* CAlo  = (ushort*)p; p += (size_t)2 * KB * KH * 2;
  ushort* WihHi = (ushort*)p; p += (size_t)3 * KH * KH * 2;
  ushort* WihLo = (ushort*)p; p += (size_t)3 * KH * KH * 2;
  ushort* WhhHi = (ushort*)p; p += (size_t)3 * KH * KH * 2;
  ushort* WhhLo = (ushort*)p; p += (size_t)3 * KH * KH * 2;
  ushort* HwHi  = (ushort*)p; p += (size_t)KA * KH * 2;
  ushort* hHi   = (ushort*)p; p += (size_t)KB * KH * 2;
  ushort* hLo   = (ushort*)p; p += (size_t)KB * KH * 2;
  float*  hbuf  = (float*)p;  p += (size_t)KB * KH * 4;
  float*  PAE   = (float*)p;  p += (size_t)2 * KB * 3 * KH * 4; // P | AE
  float*  Gh    = (float*)p;  p += (size_t)KB * 3 * KH * 4;
  ushort* Vbuf  = (ushort*)p; p += (size_t)KB * KA * 2;         // bf16 v
  unsigned char* mask  = (unsigned char*)p; p += (size_t)KB * KA;
  unsigned char* empty = (unsigned char*)p; p += (size_t)KB;
  int* idxbuf = (int*)p; p += (size_t)KB * 4;

  // Host-side JAX key schedule (partitionable split of key(42)).
  unsigned key0 = 0u, key1 = 42u;
  unsigned sub0[KL], sub1[KL];
  for (int j = 0; j < KL; ++j) {
    unsigned n0, n1, t0, t1;
    tf2x32(key0, key1, 0u, 0u, n0, n1);
    tf2x32(key0, key1, 0u, 1u, t0, t1);
    sub0[j] = t0; sub1[j] = t1;
    key0 = n0; key1 = n1;
  }

  // Preamble: all bf16 splits + empty[] in one launch.
  prep<<<PREP_CONV_BLOCKS + KB, 256, 0, stream>>>(
      w_ih, w_hh, head_w, cls, ae_w, x_,
      WihHi, WihLo, WhhHi, WhhLo, HwHi, CAhi, CAlo, empty);
  // P = cls @ w_ih^T ; AE = ae_w @ w_ih^T  (one concatenated dispatch).
  gemm3_nt<<<dim3(3 * KH / 128, 2 * KB / 128), 256, 0, stream>>>(
      CAhi, CAlo, WihHi, WihLo, PAE, 3 * KH);
  // h_0 = gate(P + b_ih, b_hh), h_prev = 0.
  gru_gate0<<<KB * KH / 4 / 256, 256, 0, stream>>>(PAE, b_ih, b_hh,
                                                   hbuf, hHi, hLo);

  for (int j = 0; j < KL; ++j) {
    const int gh_nb = (j < KL - 1) ? 576 : 0;  // Gh_{j+1} needs only h_j
    gemm_fused<<<gh_nb + 1024, 256, 0, stream>>>(
        hHi, hLo, WhhHi, WhhLo, Gh, HwHi, head_b, Vbuf, gh_nb);
    // Sample step j; fused GRU gate updates h -> h_{j+1} (rows own their idx).
    sample_gate<<<KB, 256, 0, stream>>>(
        out, Vbuf, x_, mask, idxbuf, hbuf, head_w, head_b, empty,
        PAE, Gh, b_ih, b_hh, hHi, hLo, j, (j < KL - 1) ? 1 : 0,
        sub0[j], sub1[j]);
  }
}